// Round 1
// baseline (3924.407 us; speedup 1.0000x reference)
//
#include <hip/hip_runtime.h>

#define F 128
#define LPAD 132      // LDS row stride (floats), +4 pad -> conflict-free b128 reads
#define NROWS 32      // rows per block in layer kernel

__device__ __forceinline__ float elu_f(float x) {
    return x > 0.f ? x : __expf(x) - 1.f;
}

// rp[r] = lower_bound(rows, r) for r in [0, n]; rows sorted, e entries
__global__ void rowptr_kernel(const int* __restrict__ rows, int e, int n, int* __restrict__ rp) {
    int r = blockIdx.x * blockDim.x + threadIdx.x;
    if (r > n) return;
    int lo = 0, hi = e;
    while (lo < hi) { int mid = (lo + hi) >> 1; if (rows[mid] < r) lo = mid + 1; else hi = mid; }
    rp[r] = lo;
}

__global__ void denom_kernel(const float* __restrict__ mask, int n, float* __restrict__ denom) {
    __shared__ float red[256];
    float s = 0.f;
    for (int i = threadIdx.x; i < n; i += 256) s += mask[i];
    red[threadIdx.x] = s;
    __syncthreads();
    for (int st = 128; st > 0; st >>= 1) {
        if (threadIdx.x < st) red[threadIdx.x] += red[threadIdx.x + st];
        __syncthreads();
    }
    if (threadIdx.x == 0) denom[0] = red[0];
}

// out[r][c] = sum_k in[r][k] * W[k][c] + b[c],  K=3
__global__ void conv1_kernel(const float* __restrict__ in, const float* __restrict__ W,
                             const float* __restrict__ b, float* __restrict__ out, int n) {
    int id = blockIdx.x * 256 + threadIdx.x;
    if (id >= n * F) return;
    int r = id >> 7, c = id & 127;
    out[id] = in[r * 3 + 0] * W[c] + in[r * 3 + 1] * W[F + c] + in[r * 3 + 2] * W[2 * F + c] + b[c];
}

__global__ void pool_kernel(const float* __restrict__ in, float* __restrict__ out, int nout) {
    int id = blockIdx.x * 256 + threadIdx.x;
    if (id >= nout * F) return;
    int r = id >> 7, c = id & 127;
    out[id] = fmaxf(in[(2 * r) * F + c], in[(2 * r + 1) * F + c]);
}

// out[r] = low[r/2] + skip[r]
__global__ void upadd_kernel(const float* __restrict__ low, const float* __restrict__ skip,
                             float* __restrict__ out, int nout) {
    int id = blockIdx.x * 256 + threadIdx.x;
    if (id >= nout * F) return;
    int r = id >> 7, c = id & 127;
    out[id] = low[(r >> 1) * F + c] + skip[id];
}

// bvec[c] = b[c] + sum_k (accum[k]/denom) * Wb[k][c]   (rank-1 avg term folded into bias)
__global__ void bvec_kernel(const float* __restrict__ accum, const float* __restrict__ denom,
                            const float* __restrict__ Wb, const float* __restrict__ b,
                            float* __restrict__ bvec) {
    int c = threadIdx.x;
    float inv = 1.f / denom[0];
    float s = b[c];
    for (int k = 0; k < F; ++k) s += (accum[k] * inv) * Wb[k * F + c];
    bvec[c] = s;
}

__device__ __forceinline__ void fma8(float* acc, float a, const float4& w0, const float4& w1) {
    acc[0] += a * w0.x; acc[1] += a * w0.y; acc[2] += a * w0.z; acc[3] += a * w0.w;
    acc[4] += a * w1.x; acc[5] += a * w1.y; acc[6] += a * w1.z; acc[7] += a * w1.w;
}

// acc{0,1}[8] += S[r0+{0,1}][0:128] @ W[0:128][c0:c0+8]
__device__ __forceinline__ void gemm_half(const float* S, const float* __restrict__ W,
                                          int r0, int c0, float* acc0, float* acc1) {
#pragma unroll 8
    for (int k4 = 0; k4 < 32; ++k4) {
        float4 a0 = *(const float4*)(S + (r0 + 0) * LPAD + k4 * 4);
        float4 a1 = *(const float4*)(S + (r0 + 1) * LPAD + k4 * 4);
        const float* Wk = W + k4 * 4 * F;
        float a0v[4] = {a0.x, a0.y, a0.z, a0.w};
        float a1v[4] = {a1.x, a1.y, a1.z, a1.w};
#pragma unroll
        for (int kk = 0; kk < 4; ++kk) {
            float4 w0 = *(const float4*)(Wk + kk * F + c0);
            float4 w1 = *(const float4*)(Wk + kk * F + c0 + 4);
            fma8(acc0, a0v[kk], w0, w1);
            fma8(acc1, a1v[kk], w0, w1);
        }
    }
}

// One resnet layer: OUT = elu(A)@W[0:128] + spmm(elu(A))@W[128:256] + bias (+RES)
// rowptr==nullptr -> avg mode (no spmm; avg term is pre-folded into bias).
// accum!=nullptr  -> epilogue accumulates sum_rows elu(OUT)*mask into accum[0:128].
__global__ __launch_bounds__(256)
void layer_kernel(const float* __restrict__ A, const float* RES, float* OUT,
                  const int* __restrict__ rowptr, const int* __restrict__ cols,
                  const float* __restrict__ vals,
                  const float* __restrict__ W, const float* __restrict__ bias,
                  const float* __restrict__ mask, float* accum, int n) {
    __shared__ float aS[NROWS * LPAD];
    __shared__ float sS[NROWS * LPAD];
    const int t = threadIdx.x;
    const int rbase = blockIdx.x * NROWS;
    const int f = t & 127;
    const int rh = t >> 7;

    // phase 1: stage elu(A) tile
#pragma unroll
    for (int rr = 0; rr < NROWS / 2; ++rr) {
        int lr = rr * 2 + rh;
        aS[lr * LPAD + f] = elu_f(A[(size_t)(rbase + lr) * F + f]);
    }
    // phase 2: SpMM rows (gather elu(A[col]) from global)
    if (rowptr) {
        for (int rr = 0; rr < NROWS / 2; ++rr) {
            int lr = rr * 2 + rh;
            int row = rbase + lr;
            int e0 = rowptr[row], e1 = rowptr[row + 1];
            float acc = 0.f;
            for (int e = e0; e < e1; ++e) {
                int c = cols[e];
                float v = vals[e];
                acc += v * elu_f(A[(size_t)c * F + f]);
            }
            sS[lr * LPAD + f] = acc;
        }
    }
    __syncthreads();

    // phase 3: GEMM. thread -> 2 rows x 8 cols
    const int tr = t >> 4;      // 0..15 -> rows 2tr, 2tr+1
    const int tc = t & 15;      // cols 8tc .. 8tc+7
    const int c0 = tc * 8;
    const int r0 = tr * 2;

    float acc0[8], acc1[8];
    {
        float4 b0 = *(const float4*)(bias + c0);
        float4 b1 = *(const float4*)(bias + c0 + 4);
        acc0[0] = b0.x; acc0[1] = b0.y; acc0[2] = b0.z; acc0[3] = b0.w;
        acc0[4] = b1.x; acc0[5] = b1.y; acc0[6] = b1.z; acc0[7] = b1.w;
#pragma unroll
        for (int i = 0; i < 8; ++i) acc1[i] = acc0[i];
    }
    gemm_half(aS, W, r0, c0, acc0, acc1);
    if (rowptr) gemm_half(sS, W + F * F, r0, c0, acc0, acc1);

    // residual + store
    float outv[2][8];
#pragma unroll
    for (int r = 0; r < 2; ++r) {
        float* acc = r == 0 ? acc0 : acc1;
        size_t row = (size_t)(rbase + r0 + r);
        if (RES) {
            const float4 e0 = *(const float4*)(RES + row * F + c0);
            const float4 e1 = *(const float4*)(RES + row * F + c0 + 4);
            acc[0] += e0.x; acc[1] += e0.y; acc[2] += e0.z; acc[3] += e0.w;
            acc[4] += e1.x; acc[5] += e1.y; acc[6] += e1.z; acc[7] += e1.w;
        }
        float4 o0 = make_float4(acc[0], acc[1], acc[2], acc[3]);
        float4 o1 = make_float4(acc[4], acc[5], acc[6], acc[7]);
        *(float4*)(OUT + row * F + c0) = o0;
        *(float4*)(OUT + row * F + c0 + 4) = o1;
#pragma unroll
        for (int i = 0; i < 8; ++i) outv[r][i] = acc[i];
    }

    // epilogue: masked column sums of elu(OUT) for the next avg layer
    if (accum) {
        __syncthreads();
        float m0 = mask[rbase + r0], m1 = mask[rbase + r0 + 1];
#pragma unroll
        for (int i = 0; i < 8; ++i)
            aS[tr * LPAD + c0 + i] = elu_f(outv[0][i]) * m0 + elu_f(outv[1][i]) * m1;
        __syncthreads();
        if (t < 128) {
            float s = 0.f;
            for (int q = 0; q < 16; ++q) s += aS[q * LPAD + t];
            atomicAdd(accum + t, s);
        }
    }
}

// sg = elu(XG[r])@gW2[:,0] + gb2[0] + in[r,0]; sl = elu(Y[r])@lW2 + lb2[0] + in[r,0]
// out[r]=sg; out[n+r]=sl; out[2n+r]=sig(sg)*sg + (1-sig(sg))*sl
__global__ void final_kernel(const float* __restrict__ XG, const float* __restrict__ Y,
                             const float* __restrict__ inputs,
                             const float* __restrict__ gW2, const float* __restrict__ gb2,
                             const float* __restrict__ lW2, const float* __restrict__ lb2,
                             float* __restrict__ out, int n) {
    __shared__ float sg_s[4], sl_s[4];
    int t = threadIdx.x;
    int rh = t >> 7, f = t & 127;
    size_t row = (size_t)blockIdx.x * 2 + rh;
    float pg = elu_f(XG[row * F + f]) * gW2[f * 2 + 0];
    float pl = elu_f(Y[row * F + f]) * lW2[f];
#pragma unroll
    for (int o = 32; o > 0; o >>= 1) {
        pg += __shfl_down(pg, o, 64);
        pl += __shfl_down(pl, o, 64);
    }
    int wave = t >> 6;
    if ((t & 63) == 0) { sg_s[wave] = pg; sl_s[wave] = pl; }
    __syncthreads();
    if (t < 2) {
        size_t r = (size_t)blockIdx.x * 2 + t;
        float sg = sg_s[t * 2] + sg_s[t * 2 + 1] + gb2[0] + inputs[r * 3 + 0];
        float sl = sl_s[t * 2] + sl_s[t * 2 + 1] + lb2[0] + inputs[r * 3 + 0];
        float w = 1.f / (1.f + __expf(-sg));
        out[r] = sg;
        out[n + r] = sl;
        out[2 * n + r] = w * sg + (1.f - w) * sl;
    }
}

extern "C" void kernel_launch(void* const* d_in, const int* in_sizes, int n_in,
                              void* d_out, int out_size, void* d_ws, size_t ws_size,
                              hipStream_t stream) {
    (void)in_sizes; (void)n_in; (void)out_size; (void)ws_size;
    const float* inputs = (const float*)d_in[0];
    const float* mask1  = (const float*)d_in[2];
    const int*   lrows[5] = {(const int*)d_in[3], (const int*)d_in[6], (const int*)d_in[9],
                             (const int*)d_in[12], (const int*)d_in[15]};
    const int*   lcols[5] = {(const int*)d_in[4], (const int*)d_in[7], (const int*)d_in[10],
                             (const int*)d_in[13], (const int*)d_in[16]};
    const float* lvals[5] = {(const float*)d_in[5], (const float*)d_in[8], (const float*)d_in[11],
                             (const float*)d_in[14], (const float*)d_in[17]};
    const float* gW1 = (const float*)d_in[18];
    const float* gb1 = (const float*)d_in[19];
    const float* gdW = (const float*)d_in[20];
    const float* gdb = (const float*)d_in[21];
    const float* glW = (const float*)d_in[22];
    const float* glb = (const float*)d_in[23];
    const float* guW = (const float*)d_in[24];
    const float* gub = (const float*)d_in[25];
    const float* gW2 = (const float*)d_in[26];
    const float* gb2 = (const float*)d_in[27];
    const float* lW1 = (const float*)d_in[28];
    const float* lb1 = (const float*)d_in[29];
    const float* lrW = (const float*)d_in[30];
    const float* lrb = (const float*)d_in[31];
    const float* lW2 = (const float*)d_in[32];
    const float* lb2 = (const float*)d_in[33];
    float* out = (float*)d_out;

    const int N = 16384;
    const int nlev[5] = {2048, 4096, 8192, 16384, 16384};
    const int elev[5] = {16384, 32768, 65536, 131072, 131072};

    char* ws = (char*)d_ws;
    size_t off = 0;
    auto alloc = [&](size_t bytes) -> char* {
        char* p = ws + off;
        off = (off + bytes + 255) & ~(size_t)255;
        return p;
    };
    float* BUF0 = (float*)alloc((size_t)N * F * 4);
    float* BUF1 = (float*)alloc((size_t)N * F * 4);
    float* BUF2 = (float*)alloc((size_t)N * F * 4);
    float* D8   = (float*)alloc((size_t)8192 * F * 4);
    float* D4   = (float*)alloc((size_t)4096 * F * 4);
    float* D2   = (float*)alloc((size_t)2048 * F * 4);
    int* rp[5];
    for (int i = 0; i < 5; ++i) rp[i] = (int*)alloc((size_t)(nlev[i] + 1) * 4);
    float* ACC = (float*)alloc(14 * 128 * 4);
    float* BV  = (float*)alloc(128 * 4);
    float* DEN = (float*)alloc(4);

    hipMemsetAsync(ACC, 0, 14 * 128 * 4, stream);
    for (int i = 0; i < 5; ++i)
        rowptr_kernel<<<(nlev[i] + 256) / 256, 256, 0, stream>>>(lrows[i], elev[i], nlev[i], rp[i]);
    denom_kernel<<<1, 256, 0, stream>>>(mask1, N, DEN);

    auto layer = [&](const float* A, const float* RES, float* OUT, int lap,
                     const float* W, const float* b, float* acc, int n) {
        const int* rpv = lap >= 0 ? rp[lap] : nullptr;
        const int* cl  = lap >= 0 ? lcols[lap] : nullptr;
        const float* vl = lap >= 0 ? lvals[lap] : nullptr;
        layer_kernel<<<n / NROWS, 256, 0, stream>>>(A, RES, OUT, rpv, cl, vl, W, b, mask1, acc, n);
    };

    const size_t WSZ = 256 * 128;

    // ---- global branch ----
    conv1_kernel<<<(N * F) / 256, 256, 0, stream>>>(inputs, gW1, gb1, BUF0, N);
    // down k=0 (lap3 @16384); BUF0 doubles as down[-3] save
    layer(BUF0, nullptr, BUF1, 3, gdW + 0 * WSZ, gdb + 0 * 128, nullptr, 16384);
    layer(BUF1, BUF0, BUF2, 3, gdW + 1 * WSZ, gdb + 1 * 128, nullptr, 16384);
    pool_kernel<<<(8192 * F) / 256, 256, 0, stream>>>(BUF2, D8, 8192);   // D8 = down[-2]
    layer(D8, nullptr, BUF1, 2, gdW + 2 * WSZ, gdb + 2 * 128, nullptr, 8192);
    layer(BUF1, D8, BUF2, 2, gdW + 3 * WSZ, gdb + 3 * 128, nullptr, 8192);
    pool_kernel<<<(4096 * F) / 256, 256, 0, stream>>>(BUF2, D4, 4096);   // D4 = down[-1]
    layer(D4, nullptr, BUF1, 1, gdW + 4 * WSZ, gdb + 4 * 128, nullptr, 4096);
    layer(BUF1, D4, BUF2, 1, gdW + 5 * WSZ, gdb + 5 * 128, nullptr, 4096);
    pool_kernel<<<(2048 * F) / 256, 256, 0, stream>>>(BUF2, D2, 2048);
    // bottom (lap0 @2048)
    layer(D2, nullptr, BUF1, 0, glW + 0 * WSZ, glb + 0 * 128, nullptr, 2048);
    layer(BUF1, D2, BUF2, 0, glW + 1 * WSZ, glb + 1 * 128, nullptr, 2048);
    // up i=1 @4096
    upadd_kernel<<<(4096 * F) / 256, 256, 0, stream>>>(BUF2, D4, BUF1, 4096);
    layer(BUF1, nullptr, BUF2, 1, guW + 0 * WSZ, gub + 0 * 128, nullptr, 4096);
    layer(BUF2, BUF1, D4, 1, guW + 1 * WSZ, gub + 1 * 128, nullptr, 4096);
    // up i=2 @8192
    upadd_kernel<<<(8192 * F) / 256, 256, 0, stream>>>(D4, D8, BUF1, 8192);
    layer(BUF1, nullptr, BUF2, 2, guW + 2 * WSZ, gub + 2 * 128, nullptr, 8192);
    layer(BUF2, BUF1, D8, 2, guW + 3 * WSZ, gub + 3 * 128, nullptr, 8192);
    // up i=3 @16384
    upadd_kernel<<<(N * F) / 256, 256, 0, stream>>>(D8, BUF0, BUF1, N);
    layer(BUF1, nullptr, BUF2, 3, guW + 4 * WSZ, gub + 4 * 128, nullptr, N);
    layer(BUF2, BUF1, BUF0, 3, guW + 5 * WSZ, gub + 5 * 128, nullptr, N);
    // XG = BUF0

    // ---- local branch ----
    conv1_kernel<<<(N * F) / 256, 256, 0, stream>>>(inputs, lW1, lb1, BUF1, N);
    float* cur = BUF1;
    for (int i = 0; i < 15; ++i) {
        const float* W = lrW + (size_t)i * 2 * WSZ;
        const float* b = lrb + (size_t)i * 2 * 128;
        if ((i & 1) == 0) {   // lap block on L
            layer(cur, nullptr, BUF2, 4, W, b, nullptr, N);
            float* slot = (i <= 12) ? (ACC + i * 128) : nullptr;  // feeds avg block i+1
            layer(BUF2, cur, cur, 4, W + WSZ, b + 128, slot, N);
        } else {              // avg block
            bvec_kernel<<<1, 128, 0, stream>>>(ACC + (i - 1) * 128, DEN, W + F * F, b, BV);
            layer(cur, nullptr, BUF2, -1, W, BV, ACC + i * 128, N);
            bvec_kernel<<<1, 128, 0, stream>>>(ACC + i * 128, DEN, W + WSZ + F * F, b + 128, BV);
            layer(BUF2, cur, cur, -1, W + WSZ, BV, nullptr, N);
        }
    }

    final_kernel<<<N / 2, 256, 0, stream>>>(BUF0, cur, inputs, gW2, gb2, lW2, lb2, out, N);
}

// Round 2
// 2825.660 us; speedup vs baseline: 1.3888x; 1.3888x over previous
//
#include <hip/hip_runtime.h>

#define F 128
#define KPAD 264      // bf16 elements per ES row (256 + 8 pad) -> 528B row stride
#define NR 32         // rows per block

typedef __attribute__((ext_vector_type(8))) short short8;
typedef __attribute__((ext_vector_type(16))) float f32x16;

__device__ __forceinline__ float elu_f(float x) {
    return x > 0.f ? x : __expf(x) - 1.f;
}
__device__ __forceinline__ ushort f2bf(float x) {   // fp32 -> bf16 RNE
    unsigned u = __float_as_uint(x);
    u = (u + 0x7FFFu + ((u >> 16) & 1u)) >> 16;
    return (ushort)u;
}

// rp[r] = lower_bound(rows, r) for r in [0, n]
__global__ void rowptr_kernel(const int* __restrict__ rows, int e, int n, int* __restrict__ rp) {
    int r = blockIdx.x * blockDim.x + threadIdx.x;
    if (r > n) return;
    int lo = 0, hi = e;
    while (lo < hi) { int mid = (lo + hi) >> 1; if (rows[mid] < r) lo = mid + 1; else hi = mid; }
    rp[r] = lo;
}

__global__ void denom_kernel(const float* __restrict__ mask, int n, float* __restrict__ denom) {
    __shared__ float red[256];
    float s = 0.f;
    for (int i = threadIdx.x; i < n; i += 256) s += mask[i];
    red[threadIdx.x] = s;
    __syncthreads();
    for (int st = 128; st > 0; st >>= 1) {
        if (threadIdx.x < st) red[threadIdx.x] += red[threadIdx.x + st];
        __syncthreads();
    }
    if (threadIdx.x == 0) denom[0] = red[0];
}

__global__ void conv1_kernel(const float* __restrict__ in, const float* __restrict__ W,
                             const float* __restrict__ b, float* __restrict__ out, int n) {
    int id = blockIdx.x * 256 + threadIdx.x;
    if (id >= n * F) return;
    int r = id >> 7, c = id & 127;
    out[id] = in[r * 3 + 0] * W[c] + in[r * 3 + 1] * W[F + c] + in[r * 3 + 2] * W[2 * F + c] + b[c];
}

__global__ void pool_kernel(const float* __restrict__ in, float* __restrict__ out, int nout) {
    int id = blockIdx.x * 256 + threadIdx.x;
    if (id >= nout * F) return;
    int r = id >> 7, c = id & 127;
    out[id] = fmaxf(in[(2 * r) * F + c], in[(2 * r + 1) * F + c]);
}

__global__ void upadd_kernel(const float* __restrict__ low, const float* __restrict__ skip,
                             float* __restrict__ out, int nout) {
    int id = blockIdx.x * 256 + threadIdx.x;
    if (id >= nout * F) return;
    int r = id >> 7, c = id & 127;
    out[id] = low[(r >> 1) * F + c] + skip[id];
}

// bvec[c] = b[c] + sum_k (accum[k]/denom) * Wb[k][c]   (rank-1 avg term folded into bias)
__global__ void bvec_kernel(const float* __restrict__ accum, const float* __restrict__ denom,
                            const float* __restrict__ Wb, const float* __restrict__ b,
                            float* __restrict__ bvec) {
    int c = threadIdx.x;
    float inv = 1.f / denom[0];
    float s = b[c];
    for (int k = 0; k < F; ++k) s += (accum[k] * inv) * Wb[k * F + c];
    bvec[c] = s;
}

// Pack one 128x128 fp32 W-half (row-major k x n) into 32x32x16 B-frag order, bf16.
// frag (k0 in 0..7, n0 in 0..3): dst[((k0*4+n0)*64 + lane)*8 + j] =
//   W[(k0*16 + (lane>>5)*8 + j)*128 + n0*32 + (lane&31)]
__global__ void pack_kernel(const float* __restrict__ W, ushort* __restrict__ Wp) {
    const float* src = W + (size_t)blockIdx.x * 16384;
    ushort* dst = Wp + (size_t)blockIdx.x * 16384;
    for (int idx = threadIdx.x; idx < 16384; idx += 256) {
        int j = idx & 7, lane = (idx >> 3) & 63, frag = idx >> 9;
        int k0 = frag >> 2, n0 = frag & 3;
        int k = k0 * 16 + (lane >> 5) * 8 + j;
        int nn = n0 * 32 + (lane & 31);
        dst[idx] = f2bf(src[k * 128 + nn]);
    }
}

// One resnet layer via MFMA.
// LAP=true : OUT = [elu(A), spmm(elu(A))] @ W(256x128, packed) + bias (+RES)
// LAP=false: OUT = elu(A) @ W_top(128x128, packed) + bias (+RES)  (avg term in bias)
// accum != nullptr: accum[c] += sum_rows elu(OUT[r][c]) * mask[r]
template<bool LAP>
__global__ __launch_bounds__(256)
void layer_mfma(const float* __restrict__ A, const float* RES, float* __restrict__ OUT,
                const int* __restrict__ rowptr, const int* __restrict__ cols,
                const float* __restrict__ vals,
                const ushort* __restrict__ Wp, const float* __restrict__ bias,
                const float* __restrict__ mask, float* accum, int n) {
    __shared__ ushort ES[NR * KPAD];
    const int t = threadIdx.x;
    const int rbase = blockIdx.x * NR;

    // stage E = bf16(elu(A)) tile: 32 rows x 128
    {
        int f = (t & 31) * 4;
        int rr = t >> 5;           // 0..7
#pragma unroll
        for (int p = 0; p < 4; ++p) {
            int lr = p * 8 + rr;
            float4 v = *(const float4*)(A + (size_t)(rbase + lr) * F + f);
            ushort4 o = make_ushort4(f2bf(elu_f(v.x)), f2bf(elu_f(v.y)),
                                     f2bf(elu_f(v.z)), f2bf(elu_f(v.w)));
            *(ushort4*)(&ES[lr * KPAD + f]) = o;
        }
    }
    // stage S = bf16(spmm(elu(A))) tile
    if (LAP) {
        int f = t & 127;
        int rh = t >> 7;           // 0..1
        for (int p = 0; p < 16; ++p) {
            int lr = p * 2 + rh;
            int row = rbase + lr;
            int e0 = rowptr[row], e1 = rowptr[row + 1];
            float acc = 0.f;
            for (int e = e0; e < e1; ++e)
                acc += vals[e] * elu_f(A[(size_t)cols[e] * F + f]);
            ES[lr * KPAD + 128 + f] = f2bf(acc);
        }
    }
    __syncthreads();

    // MFMA: wave w -> 32 rows x cols [w*32, w*32+32)
    const int w = t >> 6;
    const int l = t & 63;
    const int m = l & 31, kh = l >> 5;
    constexpr int KITERS = LAP ? 16 : 8;

    f32x16 acc;
#pragma unroll
    for (int i = 0; i < 16; ++i) acc[i] = 0.f;

    const ushort* esrow = &ES[m * KPAD + kh * 8];
#pragma unroll
    for (int ki = 0; ki < KITERS; ++ki) {
        short8 a = *(const short8*)(esrow + ki * 16);
        short8 b = *(const short8*)(Wp + (size_t)(ki >> 3) * 16384 +
                                    (size_t)((((ki & 7) * 4 + w) * 64 + l) * 8));
        acc = __builtin_amdgcn_mfma_f32_32x32x16_bf16(a, b, acc, 0, 0, 0);
    }

    const int col = w * 32 + m;
    const float bcol = bias[col];
    float outv[16];
#pragma unroll
    for (int reg = 0; reg < 16; ++reg) {
        int r = (reg & 3) + 8 * (reg >> 2) + 4 * kh;
        size_t rg = (size_t)(rbase + r);
        float v = acc[reg] + bcol;
        if (RES) v += RES[rg * F + col];
        OUT[rg * F + col] = v;
        outv[reg] = v;
    }
    if (accum) {
        float p = 0.f;
#pragma unroll
        for (int reg = 0; reg < 16; ++reg) {
            int r = (reg & 3) + 8 * (reg >> 2) + 4 * kh;
            p += elu_f(outv[reg]) * mask[rbase + r];
        }
        p += __shfl_xor(p, 32, 64);
        if (l < 32) atomicAdd(accum + col, p);
    }
}

__global__ void final_kernel(const float* __restrict__ XG, const float* __restrict__ Y,
                             const float* __restrict__ inputs,
                             const float* __restrict__ gW2, const float* __restrict__ gb2,
                             const float* __restrict__ lW2, const float* __restrict__ lb2,
                             float* __restrict__ out, int n) {
    __shared__ float sg_s[4], sl_s[4];
    int t = threadIdx.x;
    int rh = t >> 7, f = t & 127;
    size_t row = (size_t)blockIdx.x * 2 + rh;
    float pg = elu_f(XG[row * F + f]) * gW2[f * 2 + 0];
    float pl = elu_f(Y[row * F + f]) * lW2[f];
#pragma unroll
    for (int o = 32; o > 0; o >>= 1) {
        pg += __shfl_down(pg, o, 64);
        pl += __shfl_down(pl, o, 64);
    }
    int wave = t >> 6;
    if ((t & 63) == 0) { sg_s[wave] = pg; sl_s[wave] = pl; }
    __syncthreads();
    if (t < 2) {
        size_t r = (size_t)blockIdx.x * 2 + t;
        float sg = sg_s[t * 2] + sg_s[t * 2 + 1] + gb2[0] + inputs[r * 3 + 0];
        float sl = sl_s[t * 2] + sl_s[t * 2 + 1] + lb2[0] + inputs[r * 3 + 0];
        float wgt = 1.f / (1.f + __expf(-sg));
        out[r] = sg;
        out[n + r] = sl;
        out[2 * n + r] = wgt * sg + (1.f - wgt) * sl;
    }
}

extern "C" void kernel_launch(void* const* d_in, const int* in_sizes, int n_in,
                              void* d_out, int out_size, void* d_ws, size_t ws_size,
                              hipStream_t stream) {
    (void)in_sizes; (void)n_in; (void)out_size; (void)ws_size;
    const float* inputs = (const float*)d_in[0];
    const float* mask1  = (const float*)d_in[2];
    const int*   lrows[5] = {(const int*)d_in[3], (const int*)d_in[6], (const int*)d_in[9],
                             (const int*)d_in[12], (const int*)d_in[15]};
    const int*   lcols[5] = {(const int*)d_in[4], (const int*)d_in[7], (const int*)d_in[10],
                             (const int*)d_in[13], (const int*)d_in[16]};
    const float* lvals[5] = {(const float*)d_in[5], (const float*)d_in[8], (const float*)d_in[11],
                             (const float*)d_in[14], (const float*)d_in[17]};
    const float* gW1 = (const float*)d_in[18];
    const float* gb1 = (const float*)d_in[19];
    const float* gdW = (const float*)d_in[20];
    const float* gdb = (const float*)d_in[21];
    const float* glW = (const float*)d_in[22];
    const float* glb = (const float*)d_in[23];
    const float* guW = (const float*)d_in[24];
    const float* gub = (const float*)d_in[25];
    const float* gW2 = (const float*)d_in[26];
    const float* gb2 = (const float*)d_in[27];
    const float* lW1 = (const float*)d_in[28];
    const float* lb1 = (const float*)d_in[29];
    const float* lrW = (const float*)d_in[30];
    const float* lrb = (const float*)d_in[31];
    const float* lW2 = (const float*)d_in[32];
    const float* lb2 = (const float*)d_in[33];
    float* out = (float*)d_out;

    const int N = 16384;
    const int nlev[5] = {2048, 4096, 8192, 16384, 16384};
    const int elev[5] = {16384, 32768, 65536, 131072, 131072};

    char* ws = (char*)d_ws;
    size_t off = 0;
    auto alloc = [&](size_t bytes) -> char* {
        char* p = ws + off;
        off = (off + bytes + 255) & ~(size_t)255;
        return p;
    };
    float* BUF0 = (float*)alloc((size_t)N * F * 4);
    float* BUF1 = (float*)alloc((size_t)N * F * 4);
    float* BUF2 = (float*)alloc((size_t)N * F * 4);
    float* D8   = (float*)alloc((size_t)8192 * F * 4);
    float* D4   = (float*)alloc((size_t)4096 * F * 4);
    float* D2   = (float*)alloc((size_t)2048 * F * 4);
    int* rp[5];
    for (int i = 0; i < 5; ++i) rp[i] = (int*)alloc((size_t)(nlev[i] + 1) * 4);
    float* ACC = (float*)alloc(14 * 128 * 4);
    float* BV  = (float*)alloc(128 * 4);
    float* DEN = (float*)alloc(4);
    // packed bf16 weights: 88 halves of 16384 ushort
    ushort* Pd = (ushort*)alloc((size_t)12 * 16384 * 2);
    ushort* Pl = (ushort*)alloc((size_t)4  * 16384 * 2);
    ushort* Pu = (ushort*)alloc((size_t)12 * 16384 * 2);
    ushort* Pr = (ushort*)alloc((size_t)60 * 16384 * 2);

    hipMemsetAsync(ACC, 0, 14 * 128 * 4, stream);
    for (int i = 0; i < 5; ++i)
        rowptr_kernel<<<(nlev[i] + 256) / 256, 256, 0, stream>>>(lrows[i], elev[i], nlev[i], rp[i]);
    denom_kernel<<<1, 256, 0, stream>>>(mask1, N, DEN);
    pack_kernel<<<12, 256, 0, stream>>>(gdW, Pd);
    pack_kernel<<<4,  256, 0, stream>>>(glW, Pl);
    pack_kernel<<<12, 256, 0, stream>>>(guW, Pu);
    pack_kernel<<<60, 256, 0, stream>>>(lrW, Pr);

    auto layer = [&](const float* A, const float* RES, float* OUT, int lap,
                     const ushort* Wp, const float* b, float* acc, int n) {
        if (lap >= 0)
            layer_mfma<true><<<n / NR, 256, 0, stream>>>(A, RES, OUT, rp[lap], lcols[lap],
                                                         lvals[lap], Wp, b, mask1, acc, n);
        else
            layer_mfma<false><<<n / NR, 256, 0, stream>>>(A, RES, OUT, nullptr, nullptr,
                                                          nullptr, Wp, b, mask1, acc, n);
    };

    const size_t WSZ = 256 * 128;   // fp32 W stride per sub-layer
    const size_t PSZ = 2 * 16384;   // packed bf16 stride per sub-layer (2 halves)

    // ---- global branch ----
    conv1_kernel<<<(N * F) / 256, 256, 0, stream>>>(inputs, gW1, gb1, BUF0, N);
    layer(BUF0, nullptr, BUF1, 3, Pd + 0 * PSZ, gdb + 0 * 128, nullptr, 16384);
    layer(BUF1, BUF0, BUF2, 3, Pd + 1 * PSZ, gdb + 1 * 128, nullptr, 16384);
    pool_kernel<<<(8192 * F) / 256, 256, 0, stream>>>(BUF2, D8, 8192);
    layer(D8, nullptr, BUF1, 2, Pd + 2 * PSZ, gdb + 2 * 128, nullptr, 8192);
    layer(BUF1, D8, BUF2, 2, Pd + 3 * PSZ, gdb + 3 * 128, nullptr, 8192);
    pool_kernel<<<(4096 * F) / 256, 256, 0, stream>>>(BUF2, D4, 4096);
    layer(D4, nullptr, BUF1, 1, Pd + 4 * PSZ, gdb + 4 * 128, nullptr, 4096);
    layer(BUF1, D4, BUF2, 1, Pd + 5 * PSZ, gdb + 5 * 128, nullptr, 4096);
    pool_kernel<<<(2048 * F) / 256, 256, 0, stream>>>(BUF2, D2, 2048);
    layer(D2, nullptr, BUF1, 0, Pl + 0 * PSZ, glb + 0 * 128, nullptr, 2048);
    layer(BUF1, D2, BUF2, 0, Pl + 1 * PSZ, glb + 1 * 128, nullptr, 2048);
    upadd_kernel<<<(4096 * F) / 256, 256, 0, stream>>>(BUF2, D4, BUF1, 4096);
    layer(BUF1, nullptr, BUF2, 1, Pu + 0 * PSZ, gub + 0 * 128, nullptr, 4096);
    layer(BUF2, BUF1, D4, 1, Pu + 1 * PSZ, gub + 1 * 128, nullptr, 4096);
    upadd_kernel<<<(8192 * F) / 256, 256, 0, stream>>>(D4, D8, BUF1, 8192);
    layer(BUF1, nullptr, BUF2, 2, Pu + 2 * PSZ, gub + 2 * 128, nullptr, 8192);
    layer(BUF2, BUF1, D8, 2, Pu + 3 * PSZ, gub + 3 * 128, nullptr, 8192);
    upadd_kernel<<<(N * F) / 256, 256, 0, stream>>>(D8, BUF0, BUF1, N);
    layer(BUF1, nullptr, BUF2, 3, Pu + 4 * PSZ, gub + 4 * 128, nullptr, N);
    layer(BUF2, BUF1, BUF0, 3, Pu + 5 * PSZ, gub + 5 * 128, nullptr, N);
    // XG = BUF0

    // ---- local branch ----
    conv1_kernel<<<(N * F) / 256, 256, 0, stream>>>(inputs, lW1, lb1, BUF1, N);
    float* cur = BUF1;
    for (int i = 0; i < 15; ++i) {
        const ushort* P = Pr + (size_t)(i * 2) * PSZ;
        const float* Wf = lrW + (size_t)i * 2 * WSZ;
        const float* b = lrb + (size_t)i * 2 * 128;
        if ((i & 1) == 0) {   // lap block on L
            layer(cur, nullptr, BUF2, 4, P, b, nullptr, N);
            float* slot = (i <= 12) ? (ACC + i * 128) : nullptr;  // feeds avg block i+1
            layer(BUF2, cur, cur, 4, P + PSZ, b + 128, slot, N);
        } else {              // avg block
            bvec_kernel<<<1, 128, 0, stream>>>(ACC + (i - 1) * 128, DEN, Wf + F * F, b, BV);
            layer(cur, nullptr, BUF2, -1, P, BV, ACC + i * 128, N);
            bvec_kernel<<<1, 128, 0, stream>>>(ACC + i * 128, DEN, Wf + WSZ + F * F, b + 128, BV);
            layer(BUF2, cur, cur, -1, P + PSZ, BV, nullptr, N);
        }
    }

    final_kernel<<<N / 2, 256, 0, stream>>>(BUF0, cur, inputs, gW2, gb2, lW2, lb2, out, N);
}

// Round 3
// 1270.192 us; speedup vs baseline: 3.0896x; 2.2246x over previous
//
#include <hip/hip_runtime.h>

#define F 128
#define KPAD 264      // bf16 elements per ES row (256 + 8 pad) -> 528B row stride
#define NR 32         // rows per block

typedef __attribute__((ext_vector_type(8))) short short8;
typedef __attribute__((ext_vector_type(16))) float f32x16;

__device__ __forceinline__ float elu_f(float x) {
    return x > 0.f ? x : __expf(x) - 1.f;
}
__device__ __forceinline__ ushort f2bf(float x) {   // fp32 -> bf16 RNE
    unsigned u = __float_as_uint(x);
    u = (u + 0x7FFFu + ((u >> 16) & 1u)) >> 16;
    return (ushort)u;
}
__device__ __forceinline__ void efma4(float4& a, float v, const float4& x) {
    a.x += v * elu_f(x.x); a.y += v * elu_f(x.y);
    a.z += v * elu_f(x.z); a.w += v * elu_f(x.w);
}

// rp[r] = lower_bound(rows, r) for r in [0, n]
__global__ void rowptr_kernel(const int* __restrict__ rows, int e, int n, int* __restrict__ rp) {
    int r = blockIdx.x * blockDim.x + threadIdx.x;
    if (r > n) return;
    int lo = 0, hi = e;
    while (lo < hi) { int mid = (lo + hi) >> 1; if (rows[mid] < r) lo = mid + 1; else hi = mid; }
    rp[r] = lo;
}

__global__ void denom_kernel(const float* __restrict__ mask, int n, float* __restrict__ denom) {
    __shared__ float red[256];
    float s = 0.f;
    for (int i = threadIdx.x; i < n; i += 256) s += mask[i];
    red[threadIdx.x] = s;
    __syncthreads();
    for (int st = 128; st > 0; st >>= 1) {
        if (threadIdx.x < st) red[threadIdx.x] += red[threadIdx.x + st];
        __syncthreads();
    }
    if (threadIdx.x == 0) denom[0] = red[0];
}

__global__ void conv1_kernel(const float* __restrict__ in, const float* __restrict__ W,
                             const float* __restrict__ b, float* __restrict__ out, int n) {
    int id = blockIdx.x * 256 + threadIdx.x;
    if (id >= n * F) return;
    int r = id >> 7, c = id & 127;
    out[id] = in[r * 3 + 0] * W[c] + in[r * 3 + 1] * W[F + c] + in[r * 3 + 2] * W[2 * F + c] + b[c];
}

__global__ void pool_kernel(const float* __restrict__ in, float* __restrict__ out, int nout) {
    int id = blockIdx.x * 256 + threadIdx.x;
    if (id >= nout * F) return;
    int r = id >> 7, c = id & 127;
    out[id] = fmaxf(in[(2 * r) * F + c], in[(2 * r + 1) * F + c]);
}

__global__ void upadd_kernel(const float* __restrict__ low, const float* __restrict__ skip,
                             float* __restrict__ out, int nout) {
    int id = blockIdx.x * 256 + threadIdx.x;
    if (id >= nout * F) return;
    int r = id >> 7, c = id & 127;
    out[id] = low[(r >> 1) * F + c] + skip[id];
}

// bvec[c] = b[c] + sum_k (accum[k]/denom) * Wb[k][c]   (rank-1 avg term folded into bias)
__global__ void bvec_kernel(const float* __restrict__ accum, const float* __restrict__ denom,
                            const float* __restrict__ Wb, const float* __restrict__ b,
                            float* __restrict__ bvec) {
    int c = threadIdx.x;
    float inv = 1.f / denom[0];
    float s = b[c];
#pragma unroll 4
    for (int k = 0; k < F; ++k) s += (accum[k] * inv) * Wb[k * F + c];
    bvec[c] = s;
}

// Pack one 128x128 fp32 W-half (row-major k x n) into 32x32x16 B-frag order, bf16.
__global__ void pack_kernel(const float* __restrict__ W, ushort* __restrict__ Wp) {
    const float* src = W + (size_t)blockIdx.x * 16384;
    ushort* dst = Wp + (size_t)blockIdx.x * 16384;
    for (int idx = threadIdx.x; idx < 16384; idx += 256) {
        int j = idx & 7, lane = (idx >> 3) & 63, frag = idx >> 9;
        int k0 = frag >> 2, n0 = frag & 3;
        int k = k0 * 16 + (lane >> 5) * 8 + j;
        int nn = n0 * 32 + (lane & 31);
        dst[idx] = f2bf(src[k * 128 + nn]);
    }
}

// One resnet layer via MFMA.
// LAP=true : OUT = [elu(A), spmm(elu(A))] @ W(256x128, packed) + bias (+RES)
// LAP=false: OUT = elu(A) @ W_top(128x128, packed) + bias (+RES)  (avg term in bias)
// accum != nullptr: accum[c] += sum_rows elu(OUT[r][c]) * mask[r]
template<bool LAP>
__global__ __launch_bounds__(256)
void layer_mfma(const float* __restrict__ A, const float* RES, float* __restrict__ OUT,
                const int* __restrict__ rowptr, const int* __restrict__ cols,
                const float* __restrict__ vals,
                const ushort* __restrict__ Wp, const float* __restrict__ bias,
                const float* __restrict__ mask, float* accum, int n) {
    __shared__ ushort ES[NR * KPAD];
    const int t = threadIdx.x;
    const int rbase = blockIdx.x * NR;

    // stage E = bf16(elu(A)) tile: 32 rows x 128
    {
        int f = (t & 31) * 4;
        int rr = t >> 5;           // 0..7
#pragma unroll
        for (int p = 0; p < 4; ++p) {
            int lr = p * 8 + rr;
            float4 v = *(const float4*)(A + (size_t)(rbase + lr) * F + f);
            ushort4 o = make_ushort4(f2bf(elu_f(v.x)), f2bf(elu_f(v.y)),
                                     f2bf(elu_f(v.z)), f2bf(elu_f(v.w)));
            *(ushort4*)(&ES[lr * KPAD + f]) = o;
        }
    }
    // stage S = bf16(spmm(elu(A))): 32-lane groups, float4 gathers, 4-deep ILP
    if (LAP) {
        const int g = t >> 5;          // 0..7
        const int lane = t & 31;       // float4 index within row
        const float4* A4 = (const float4*)A;
#pragma unroll
        for (int p = 0; p < 4; ++p) {
            int lr = g + p * 8;
            int row = rbase + lr;
            int e0 = rowptr[row], e1 = rowptr[row + 1];
            float4 acc0 = make_float4(0.f, 0.f, 0.f, 0.f);
            float4 acc1 = acc0, acc2 = acc0, acc3 = acc0;
            int e = e0;
            for (; e + 4 <= e1; e += 4) {
                int c0 = cols[e + 0], c1 = cols[e + 1], c2 = cols[e + 2], c3 = cols[e + 3];
                float v0 = vals[e + 0], v1 = vals[e + 1], v2 = vals[e + 2], v3 = vals[e + 3];
                float4 a0 = A4[(size_t)c0 * 32 + lane];
                float4 a1 = A4[(size_t)c1 * 32 + lane];
                float4 a2 = A4[(size_t)c2 * 32 + lane];
                float4 a3 = A4[(size_t)c3 * 32 + lane];
                efma4(acc0, v0, a0); efma4(acc1, v1, a1);
                efma4(acc2, v2, a2); efma4(acc3, v3, a3);
            }
            for (; e < e1; ++e) {
                int c = cols[e];
                float v = vals[e];
                float4 a = A4[(size_t)c * 32 + lane];
                efma4(acc0, v, a);
            }
            float4 s = make_float4(acc0.x + acc1.x + acc2.x + acc3.x,
                                   acc0.y + acc1.y + acc2.y + acc3.y,
                                   acc0.z + acc1.z + acc2.z + acc3.z,
                                   acc0.w + acc1.w + acc2.w + acc3.w);
            ushort4 o = make_ushort4(f2bf(s.x), f2bf(s.y), f2bf(s.z), f2bf(s.w));
            *(ushort4*)(&ES[lr * KPAD + 128 + lane * 4]) = o;
        }
    }
    __syncthreads();

    // MFMA: wave w -> 32 rows x cols [w*32, w*32+32)
    const int w = t >> 6;
    const int l = t & 63;
    const int m = l & 31, kh = l >> 5;
    constexpr int KITERS = LAP ? 16 : 8;

    f32x16 acc;
#pragma unroll
    for (int i = 0; i < 16; ++i) acc[i] = 0.f;

    const ushort* esrow = &ES[m * KPAD + kh * 8];
#pragma unroll
    for (int ki = 0; ki < KITERS; ++ki) {
        short8 a = *(const short8*)(esrow + ki * 16);
        short8 b = *(const short8*)(Wp + (size_t)(ki >> 3) * 16384 +
                                    (size_t)((((ki & 7) * 4 + w) * 64 + l) * 8));
        acc = __builtin_amdgcn_mfma_f32_32x32x16_bf16(a, b, acc, 0, 0, 0);
    }

    const int col = w * 32 + m;
    const float bcol = bias[col];
    float outv[16];
#pragma unroll
    for (int reg = 0; reg < 16; ++reg) {
        int r = (reg & 3) + 8 * (reg >> 2) + 4 * kh;
        size_t rg = (size_t)(rbase + r);
        float v = acc[reg] + bcol;
        if (RES) v += RES[rg * F + col];
        OUT[rg * F + col] = v;
        outv[reg] = v;
    }
    if (accum) {
        float p = 0.f;
#pragma unroll
        for (int reg = 0; reg < 16; ++reg) {
            int r = (reg & 3) + 8 * (reg >> 2) + 4 * kh;
            p += elu_f(outv[reg]) * mask[rbase + r];
        }
        p += __shfl_xor(p, 32, 64);
        if (l < 32) atomicAdd(accum + col, p);
    }
}

__global__ void final_kernel(const float* __restrict__ XG, const float* __restrict__ Y,
                             const float* __restrict__ inputs,
                             const float* __restrict__ gW2, const float* __restrict__ gb2,
                             const float* __restrict__ lW2, const float* __restrict__ lb2,
                             float* __restrict__ out, int n) {
    __shared__ float sg_s[4], sl_s[4];
    int t = threadIdx.x;
    int rh = t >> 7, f = t & 127;
    size_t row = (size_t)blockIdx.x * 2 + rh;
    float pg = elu_f(XG[row * F + f]) * gW2[f * 2 + 0];
    float pl = elu_f(Y[row * F + f]) * lW2[f];
#pragma unroll
    for (int o = 32; o > 0; o >>= 1) {
        pg += __shfl_down(pg, o, 64);
        pl += __shfl_down(pl, o, 64);
    }
    int wave = t >> 6;
    if ((t & 63) == 0) { sg_s[wave] = pg; sl_s[wave] = pl; }
    __syncthreads();
    if (t < 2) {
        size_t r = (size_t)blockIdx.x * 2 + t;
        float sg = sg_s[t * 2] + sg_s[t * 2 + 1] + gb2[0] + inputs[r * 3 + 0];
        float sl = sl_s[t * 2] + sl_s[t * 2 + 1] + lb2[0] + inputs[r * 3 + 0];
        float wgt = 1.f / (1.f + __expf(-sg));
        out[r] = sg;
        out[n + r] = sl;
        out[2 * n + r] = wgt * sg + (1.f - wgt) * sl;
    }
}

extern "C" void kernel_launch(void* const* d_in, const int* in_sizes, int n_in,
                              void* d_out, int out_size, void* d_ws, size_t ws_size,
                              hipStream_t stream) {
    (void)in_sizes; (void)n_in; (void)out_size; (void)ws_size;
    const float* inputs = (const float*)d_in[0];
    const float* mask1  = (const float*)d_in[2];
    const int*   lrows[5] = {(const int*)d_in[3], (const int*)d_in[6], (const int*)d_in[9],
                             (const int*)d_in[12], (const int*)d_in[15]};
    const int*   lcols[5] = {(const int*)d_in[4], (const int*)d_in[7], (const int*)d_in[10],
                             (const int*)d_in[13], (const int*)d_in[16]};
    const float* lvals[5] = {(const float*)d_in[5], (const float*)d_in[8], (const float*)d_in[11],
                             (const float*)d_in[14], (const float*)d_in[17]};
    const float* gW1 = (const float*)d_in[18];
    const float* gb1 = (const float*)d_in[19];
    const float* gdW = (const float*)d_in[20];
    const float* gdb = (const float*)d_in[21];
    const float* glW = (const float*)d_in[22];
    const float* glb = (const float*)d_in[23];
    const float* guW = (const float*)d_in[24];
    const float* gub = (const float*)d_in[25];
    const float* gW2 = (const float*)d_in[26];
    const float* gb2 = (const float*)d_in[27];
    const float* lW1 = (const float*)d_in[28];
    const float* lb1 = (const float*)d_in[29];
    const float* lrW = (const float*)d_in[30];
    const float* lrb = (const float*)d_in[31];
    const float* lW2 = (const float*)d_in[32];
    const float* lb2 = (const float*)d_in[33];
    float* out = (float*)d_out;

    const int N = 16384;
    const int nlev[5] = {2048, 4096, 8192, 16384, 16384};
    const int elev[5] = {16384, 32768, 65536, 131072, 131072};

    char* ws = (char*)d_ws;
    size_t off = 0;
    auto alloc = [&](size_t bytes) -> char* {
        char* p = ws + off;
        off = (off + bytes + 255) & ~(size_t)255;
        return p;
    };
    float* BUF0 = (float*)alloc((size_t)N * F * 4);
    float* BUF1 = (float*)alloc((size_t)N * F * 4);
    float* BUF2 = (float*)alloc((size_t)N * F * 4);
    float* D8   = (float*)alloc((size_t)8192 * F * 4);
    float* D4   = (float*)alloc((size_t)4096 * F * 4);
    float* D2   = (float*)alloc((size_t)2048 * F * 4);
    int* rp[5];
    for (int i = 0; i < 5; ++i) rp[i] = (int*)alloc((size_t)(nlev[i] + 1) * 4);
    float* ACC = (float*)alloc(14 * 128 * 4);
    float* BV  = (float*)alloc(128 * 4);
    float* DEN = (float*)alloc(4);
    // packed bf16 weights: 88 halves of 16384 ushort
    ushort* Pd = (ushort*)alloc((size_t)12 * 16384 * 2);
    ushort* Pl = (ushort*)alloc((size_t)4  * 16384 * 2);
    ushort* Pu = (ushort*)alloc((size_t)12 * 16384 * 2);
    ushort* Pr = (ushort*)alloc((size_t)60 * 16384 * 2);

    hipMemsetAsync(ACC, 0, 14 * 128 * 4, stream);
    for (int i = 0; i < 5; ++i)
        rowptr_kernel<<<(nlev[i] + 256) / 256, 256, 0, stream>>>(lrows[i], elev[i], nlev[i], rp[i]);
    denom_kernel<<<1, 256, 0, stream>>>(mask1, N, DEN);
    pack_kernel<<<12, 256, 0, stream>>>(gdW, Pd);
    pack_kernel<<<4,  256, 0, stream>>>(glW, Pl);
    pack_kernel<<<12, 256, 0, stream>>>(guW, Pu);
    pack_kernel<<<60, 256, 0, stream>>>(lrW, Pr);

    auto layer = [&](const float* A, const float* RES, float* OUT, int lap,
                     const ushort* Wp, const float* b, float* acc, int n) {
        if (lap >= 0)
            layer_mfma<true><<<n / NR, 256, 0, stream>>>(A, RES, OUT, rp[lap], lcols[lap],
                                                         lvals[lap], Wp, b, mask1, acc, n);
        else
            layer_mfma<false><<<n / NR, 256, 0, stream>>>(A, RES, OUT, nullptr, nullptr,
                                                          nullptr, Wp, b, mask1, acc, n);
    };

    const size_t WSZ = 256 * 128;   // fp32 W stride per sub-layer
    const size_t PSZ = 2 * 16384;   // packed bf16 stride per sub-layer (2 halves)

    // ---- global branch ----
    conv1_kernel<<<(N * F) / 256, 256, 0, stream>>>(inputs, gW1, gb1, BUF0, N);
    layer(BUF0, nullptr, BUF1, 3, Pd + 0 * PSZ, gdb + 0 * 128, nullptr, 16384);
    layer(BUF1, BUF0, BUF2, 3, Pd + 1 * PSZ, gdb + 1 * 128, nullptr, 16384);
    pool_kernel<<<(8192 * F) / 256, 256, 0, stream>>>(BUF2, D8, 8192);
    layer(D8, nullptr, BUF1, 2, Pd + 2 * PSZ, gdb + 2 * 128, nullptr, 8192);
    layer(BUF1, D8, BUF2, 2, Pd + 3 * PSZ, gdb + 3 * 128, nullptr, 8192);
    pool_kernel<<<(4096 * F) / 256, 256, 0, stream>>>(BUF2, D4, 4096);
    layer(D4, nullptr, BUF1, 1, Pd + 4 * PSZ, gdb + 4 * 128, nullptr, 4096);
    layer(BUF1, D4, BUF2, 1, Pd + 5 * PSZ, gdb + 5 * 128, nullptr, 4096);
    pool_kernel<<<(2048 * F) / 256, 256, 0, stream>>>(BUF2, D2, 2048);
    layer(D2, nullptr, BUF1, 0, Pl + 0 * PSZ, glb + 0 * 128, nullptr, 2048);
    layer(BUF1, D2, BUF2, 0, Pl + 1 * PSZ, glb + 1 * 128, nullptr, 2048);
    upadd_kernel<<<(4096 * F) / 256, 256, 0, stream>>>(BUF2, D4, BUF1, 4096);
    layer(BUF1, nullptr, BUF2, 1, Pu + 0 * PSZ, gub + 0 * 128, nullptr, 4096);
    layer(BUF2, BUF1, D4, 1, Pu + 1 * PSZ, gub + 1 * 128, nullptr, 4096);
    upadd_kernel<<<(8192 * F) / 256, 256, 0, stream>>>(D4, D8, BUF1, 8192);
    layer(BUF1, nullptr, BUF2, 2, Pu + 2 * PSZ, gub + 2 * 128, nullptr, 8192);
    layer(BUF2, BUF1, D8, 2, Pu + 3 * PSZ, gub + 3 * 128, nullptr, 8192);
    upadd_kernel<<<(N * F) / 256, 256, 0, stream>>>(D8, BUF0, BUF1, N);
    layer(BUF1, nullptr, BUF2, 3, Pu + 4 * PSZ, gub + 4 * 128, nullptr, N);
    layer(BUF2, BUF1, BUF0, 3, Pu + 5 * PSZ, gub + 5 * 128, nullptr, N);
    // XG = BUF0

    // ---- local branch ----
    conv1_kernel<<<(N * F) / 256, 256, 0, stream>>>(inputs, lW1, lb1, BUF1, N);
    float* cur = BUF1;
    for (int i = 0; i < 15; ++i) {
        const ushort* P = Pr + (size_t)(i * 2) * PSZ;
        const float* Wf = lrW + (size_t)i * 2 * WSZ;
        const float* b = lrb + (size_t)i * 2 * 128;
        if ((i & 1) == 0) {   // lap block on L
            layer(cur, nullptr, BUF2, 4, P, b, nullptr, N);
            float* slot = (i <= 12) ? (ACC + i * 128) : nullptr;  // feeds avg block i+1
            layer(BUF2, cur, cur, 4, P + PSZ, b + 128, slot, N);
        } else {              // avg block
            bvec_kernel<<<1, 128, 0, stream>>>(ACC + (i - 1) * 128, DEN, Wf + F * F, b, BV);
            layer(cur, nullptr, BUF2, -1, P, BV, ACC + i * 128, N);
            bvec_kernel<<<1, 128, 0, stream>>>(ACC + i * 128, DEN, Wf + WSZ + F * F, b + 128, BV);
            layer(BUF2, cur, cur, -1, P + PSZ, BV, nullptr, N);
        }
    }

    final_kernel<<<N / 2, 256, 0, stream>>>(BUF0, cur, inputs, gW2, gb2, lW2, lb2, out, N);
}

// Round 4
// 1260.161 us; speedup vs baseline: 3.1142x; 1.0080x over previous
//
#include <hip/hip_runtime.h>

#define F 128
#define SPAD 136      // LDS stride (ushorts) for S tile: 272 B = 17*16B
#define NR 32         // rows per block

typedef __attribute__((ext_vector_type(8))) short short8;
typedef __attribute__((ext_vector_type(16))) float f32x16;

__device__ __forceinline__ float elu_f(float x) {
    return x > 0.f ? x : __expf(x) - 1.f;
}
__device__ __forceinline__ ushort f2bf(float x) {   // fp32 -> bf16 RNE
    unsigned u = __float_as_uint(x);
    u = (u + 0x7FFFu + ((u >> 16) & 1u)) >> 16;
    return (ushort)u;
}
__device__ __forceinline__ float bf2f(ushort u) {
    return __uint_as_float((unsigned)u << 16);
}
__device__ __forceinline__ void bfma4(float4& a, float v, const ushort4& u) {
    a.x += v * bf2f(u.x); a.y += v * bf2f(u.y);
    a.z += v * bf2f(u.z); a.w += v * bf2f(u.w);
}

// rp[r] = lower_bound(rows, r) for r in [0, n]
__global__ void rowptr_kernel(const int* __restrict__ rows, int e, int n, int* __restrict__ rp) {
    int r = blockIdx.x * blockDim.x + threadIdx.x;
    if (r > n) return;
    int lo = 0, hi = e;
    while (lo < hi) { int mid = (lo + hi) >> 1; if (rows[mid] < r) lo = mid + 1; else hi = mid; }
    rp[r] = lo;
}

__global__ void denom_kernel(const float* __restrict__ mask, int n, float* __restrict__ denom) {
    __shared__ float red[256];
    float s = 0.f;
    for (int i = threadIdx.x; i < n; i += 256) s += mask[i];
    red[threadIdx.x] = s;
    __syncthreads();
    for (int st = 128; st > 0; st >>= 1) {
        if (threadIdx.x < st) red[threadIdx.x] += red[threadIdx.x + st];
        __syncthreads();
    }
    if (threadIdx.x == 0) denom[0] = red[0];
}

// out[r][c] = in[r]@W + b; ea = bf16(elu(out))
__global__ void conv1_kernel(const float* __restrict__ in, const float* __restrict__ W,
                             const float* __restrict__ b, float* __restrict__ out,
                             ushort* __restrict__ ea, int n) {
    int id = blockIdx.x * 256 + threadIdx.x;
    if (id >= n * F) return;
    int r = id >> 7, c = id & 127;
    float o = in[r * 3 + 0] * W[c] + in[r * 3 + 1] * W[F + c] + in[r * 3 + 2] * W[2 * F + c] + b[c];
    out[id] = o;
    ea[id] = f2bf(elu_f(o));
}

__global__ void pool_kernel(const float* __restrict__ in, float* __restrict__ out,
                            ushort* __restrict__ ea, int nout) {
    int id = blockIdx.x * 256 + threadIdx.x;
    if (id >= nout * F) return;
    int r = id >> 7, c = id & 127;
    float o = fmaxf(in[(2 * r) * F + c], in[(2 * r + 1) * F + c]);
    out[id] = o;
    ea[id] = f2bf(elu_f(o));
}

// out[r] = low[r/2] + skip[r]; ea = bf16(elu(out))
__global__ void upadd_kernel(const float* __restrict__ low, const float* __restrict__ skip,
                             float* __restrict__ out, ushort* __restrict__ ea, int nout) {
    int id = blockIdx.x * 256 + threadIdx.x;
    if (id >= nout * F) return;
    int r = id >> 7, c = id & 127;
    float o = low[(r >> 1) * F + c] + skip[id];
    out[id] = o;
    ea[id] = f2bf(elu_f(o));
}

// Pack one 128x128 fp32 W-half (row-major k x n) into 32x32x16 B-frag order, bf16.
__global__ void pack_kernel(const float* __restrict__ W, ushort* __restrict__ Wp) {
    const float* src = W + (size_t)blockIdx.x * 16384;
    ushort* dst = Wp + (size_t)blockIdx.x * 16384;
    for (int idx = threadIdx.x; idx < 16384; idx += 256) {
        int j = idx & 7, lane = (idx >> 3) & 63, frag = idx >> 9;
        int k0 = frag >> 2, n0 = frag & 3;
        int k = k0 * 16 + (lane >> 5) * 8 + j;
        int nn = n0 * 32 + (lane & 31);
        dst[idx] = f2bf(src[k * 128 + nn]);
    }
}

// One resnet layer via MFMA, bf16-elu activation mirror (EA) in/out.
// LAP=true : OUT = [eluA, spmm(eluA)] @ W(256x128 packed) + bias (+RES)
// LAP=false: OUT = eluA @ W_top + bias (+RES); avg term folded via accin/Wb/den.
// EAOUT != nullptr: EAOUT = bf16(elu(OUT)).  accout != nullptr: accout[c] += sum elu(OUT)*mask.
template<bool LAP>
__global__ __launch_bounds__(256)
void layer_mfma(const ushort* __restrict__ EA, const float* RES,
                float* __restrict__ OUT, ushort* EAOUT,
                const int* __restrict__ rowptr, const int* __restrict__ cols,
                const float* __restrict__ vals,
                const ushort* __restrict__ Wp, const float* __restrict__ bias,
                const float* accin, const float* __restrict__ Wb, const float* den,
                const float* __restrict__ mask, float* accout, int n) {
    extern __shared__ ushort SS[];     // LAP: NR x SPAD bf16 spmm tile
    const int t = threadIdx.x;
    const int rbase = blockIdx.x * NR;
    const int w = t >> 6, l = t & 63, m = l & 31, kh = l >> 5;
    const int col = w * 32 + m;

    if constexpr (LAP) {
        // gather spmm rows from EA (bf16, elu pre-applied): 32-lane groups, 4-deep ILP
        const int g = t >> 5;
        const int lane = t & 31;
        const ushort4* EA4 = (const ushort4*)EA;   // 32 ushort4 per row
#pragma unroll
        for (int p = 0; p < 4; ++p) {
            int lr = g + p * 8;
            int row = rbase + lr;
            int e0 = rowptr[row], e1 = rowptr[row + 1];
            float4 a0 = make_float4(0.f, 0.f, 0.f, 0.f);
            float4 a1 = a0, a2 = a0, a3 = a0;
            int e = e0;
            for (; e + 4 <= e1; e += 4) {
                int c0 = cols[e + 0], c1 = cols[e + 1], c2 = cols[e + 2], c3 = cols[e + 3];
                float v0 = vals[e + 0], v1 = vals[e + 1], v2 = vals[e + 2], v3 = vals[e + 3];
                ushort4 u0 = EA4[(size_t)c0 * 32 + lane];
                ushort4 u1 = EA4[(size_t)c1 * 32 + lane];
                ushort4 u2 = EA4[(size_t)c2 * 32 + lane];
                ushort4 u3 = EA4[(size_t)c3 * 32 + lane];
                bfma4(a0, v0, u0); bfma4(a1, v1, u1);
                bfma4(a2, v2, u2); bfma4(a3, v3, u3);
            }
            for (; e < e1; ++e) {
                ushort4 u = EA4[(size_t)cols[e] * 32 + lane];
                bfma4(a0, vals[e], u);
            }
            float4 s = make_float4(a0.x + a1.x + a2.x + a3.x,
                                   a0.y + a1.y + a2.y + a3.y,
                                   a0.z + a1.z + a2.z + a3.z,
                                   a0.w + a1.w + a2.w + a3.w);
            ushort4 o = make_ushort4(f2bf(s.x), f2bf(s.y), f2bf(s.z), f2bf(s.w));
            *(ushort4*)(&SS[lr * SPAD + lane * 4]) = o;
        }
        __syncthreads();
    }

    // per-col bias (+ folded rank-1 avg term for avg layers)
    float bv = bias[col];
    if (accin) {
        float inv = 1.f / den[0];
#pragma unroll 4
        for (int k = 0; k < F; ++k) bv += (accin[k] * inv) * Wb[k * F + col];
    }

    f32x16 acc;
#pragma unroll
    for (int i = 0; i < 16; ++i) acc[i] = 0.f;

    // dense half: A-fragments straight from EA global (frag-exact layout)
    const ushort* ear = EA + (size_t)(rbase + m) * F + kh * 8;
#pragma unroll
    for (int ki = 0; ki < 8; ++ki) {
        short8 a = *(const short8*)(ear + ki * 16);
        short8 b = *(const short8*)(Wp + (size_t)(((ki * 4 + w) * 64 + l) * 8));
        acc = __builtin_amdgcn_mfma_f32_32x32x16_bf16(a, b, acc, 0, 0, 0);
    }
    if constexpr (LAP) {
        const ushort* ssr = &SS[m * SPAD + kh * 8];
#pragma unroll
        for (int ki = 0; ki < 8; ++ki) {
            short8 a = *(const short8*)(ssr + ki * 16);
            short8 b = *(const short8*)(Wp + 16384 + (size_t)(((ki * 4 + w) * 64 + l) * 8));
            acc = __builtin_amdgcn_mfma_f32_32x32x16_bf16(a, b, acc, 0, 0, 0);
        }
    }

    float outv[16];
#pragma unroll
    for (int reg = 0; reg < 16; ++reg) {
        int r = (reg & 3) + 8 * (reg >> 2) + 4 * kh;
        size_t rg = (size_t)(rbase + r);
        float v = acc[reg] + bv;
        if (RES) v += RES[rg * F + col];
        OUT[rg * F + col] = v;
        outv[reg] = v;
    }
    if (EAOUT || accout) {
        float ev[16];
#pragma unroll
        for (int reg = 0; reg < 16; ++reg) ev[reg] = elu_f(outv[reg]);
        if (EAOUT) {
#pragma unroll
            for (int reg = 0; reg < 16; ++reg) {
                int r = (reg & 3) + 8 * (reg >> 2) + 4 * kh;
                EAOUT[(size_t)(rbase + r) * F + col] = f2bf(ev[reg]);
            }
        }
        if (accout) {
            float p = 0.f;
#pragma unroll
            for (int reg = 0; reg < 16; ++reg) {
                int r = (reg & 3) + 8 * (reg >> 2) + 4 * kh;
                p += ev[reg] * mask[rbase + r];
            }
            p += __shfl_xor(p, 32, 64);
            if (l < 32) atomicAdd(accout + col, p);
        }
    }
}

// reads bf16-elu mirrors of XG and Y directly
__global__ void final_kernel(const ushort* __restrict__ EAX, const ushort* __restrict__ EAY,
                             const float* __restrict__ inputs,
                             const float* __restrict__ gW2, const float* __restrict__ gb2,
                             const float* __restrict__ lW2, const float* __restrict__ lb2,
                             float* __restrict__ out, int n) {
    __shared__ float sg_s[4], sl_s[4];
    int t = threadIdx.x;
    int rh = t >> 7, f = t & 127;
    size_t row = (size_t)blockIdx.x * 2 + rh;
    float pg = bf2f(EAX[row * F + f]) * gW2[f * 2 + 0];
    float pl = bf2f(EAY[row * F + f]) * lW2[f];
#pragma unroll
    for (int o = 32; o > 0; o >>= 1) {
        pg += __shfl_down(pg, o, 64);
        pl += __shfl_down(pl, o, 64);
    }
    int wave = t >> 6;
    if ((t & 63) == 0) { sg_s[wave] = pg; sl_s[wave] = pl; }
    __syncthreads();
    if (t < 2) {
        size_t r = (size_t)blockIdx.x * 2 + t;
        float sg = sg_s[t * 2] + sg_s[t * 2 + 1] + gb2[0] + inputs[r * 3 + 0];
        float sl = sl_s[t * 2] + sl_s[t * 2 + 1] + lb2[0] + inputs[r * 3 + 0];
        float wgt = 1.f / (1.f + __expf(-sg));
        out[r] = sg;
        out[n + r] = sl;
        out[2 * n + r] = wgt * sg + (1.f - wgt) * sl;
    }
}

extern "C" void kernel_launch(void* const* d_in, const int* in_sizes, int n_in,
                              void* d_out, int out_size, void* d_ws, size_t ws_size,
                              hipStream_t stream) {
    (void)in_sizes; (void)n_in; (void)out_size; (void)ws_size;
    const float* inputs = (const float*)d_in[0];
    const float* mask1  = (const float*)d_in[2];
    const int*   lrows[5] = {(const int*)d_in[3], (const int*)d_in[6], (const int*)d_in[9],
                             (const int*)d_in[12], (const int*)d_in[15]};
    const int*   lcols[5] = {(const int*)d_in[4], (const int*)d_in[7], (const int*)d_in[10],
                             (const int*)d_in[13], (const int*)d_in[16]};
    const float* lvals[5] = {(const float*)d_in[5], (const float*)d_in[8], (const float*)d_in[11],
                             (const float*)d_in[14], (const float*)d_in[17]};
    const float* gW1 = (const float*)d_in[18];
    const float* gb1 = (const float*)d_in[19];
    const float* gdW = (const float*)d_in[20];
    const float* gdb = (const float*)d_in[21];
    const float* glW = (const float*)d_in[22];
    const float* glb = (const float*)d_in[23];
    const float* guW = (const float*)d_in[24];
    const float* gub = (const float*)d_in[25];
    const float* gW2 = (const float*)d_in[26];
    const float* gb2 = (const float*)d_in[27];
    const float* lW1 = (const float*)d_in[28];
    const float* lb1 = (const float*)d_in[29];
    const float* lrW = (const float*)d_in[30];
    const float* lrb = (const float*)d_in[31];
    const float* lW2 = (const float*)d_in[32];
    const float* lb2 = (const float*)d_in[33];
    float* out = (float*)d_out;

    const int N = 16384;
    const int nlev[5] = {2048, 4096, 8192, 16384, 16384};
    const int elev[5] = {16384, 32768, 65536, 131072, 131072};

    char* ws = (char*)d_ws;
    size_t off = 0;
    auto alloc = [&](size_t bytes) -> char* {
        char* p = ws + off;
        off = (off + bytes + 255) & ~(size_t)255;
        return p;
    };
    float* BUF0 = (float*)alloc((size_t)N * F * 4);
    float* BUF1 = (float*)alloc((size_t)N * F * 4);
    float* BUF2 = (float*)alloc((size_t)N * F * 4);
    float* D8   = (float*)alloc((size_t)8192 * F * 4);
    float* D4   = (float*)alloc((size_t)4096 * F * 4);
    float* D2   = (float*)alloc((size_t)2048 * F * 4);
    // bf16 elu mirrors
    ushort* EB0 = (ushort*)alloc((size_t)N * F * 2);
    ushort* EB1 = (ushort*)alloc((size_t)N * F * 2);
    ushort* EB2 = (ushort*)alloc((size_t)N * F * 2);
    ushort* ED8 = (ushort*)alloc((size_t)8192 * F * 2);
    ushort* ED4 = (ushort*)alloc((size_t)4096 * F * 2);
    ushort* ED2 = (ushort*)alloc((size_t)2048 * F * 2);
    int* rp[5];
    for (int i = 0; i < 5; ++i) rp[i] = (int*)alloc((size_t)(nlev[i] + 1) * 4);
    float* ACC = (float*)alloc(14 * 128 * 4);
    float* DEN = (float*)alloc(4);
    ushort* Pd = (ushort*)alloc((size_t)12 * 16384 * 2);
    ushort* Pl = (ushort*)alloc((size_t)4  * 16384 * 2);
    ushort* Pu = (ushort*)alloc((size_t)12 * 16384 * 2);
    ushort* Pr = (ushort*)alloc((size_t)60 * 16384 * 2);

    hipMemsetAsync(ACC, 0, 14 * 128 * 4, stream);
    for (int i = 0; i < 5; ++i)
        rowptr_kernel<<<(nlev[i] + 256) / 256, 256, 0, stream>>>(lrows[i], elev[i], nlev[i], rp[i]);
    denom_kernel<<<1, 256, 0, stream>>>(mask1, N, DEN);
    pack_kernel<<<12, 256, 0, stream>>>(gdW, Pd);
    pack_kernel<<<4,  256, 0, stream>>>(glW, Pl);
    pack_kernel<<<12, 256, 0, stream>>>(guW, Pu);
    pack_kernel<<<60, 256, 0, stream>>>(lrW, Pr);

    const size_t SMEM = (size_t)NR * SPAD * 2;

    // lap layer
    auto lap = [&](const ushort* ea, const float* res, float* o, ushort* eao, int lv,
                   const ushort* Wp, const float* b, float* acc, int n) {
        layer_mfma<true><<<n / NR, 256, SMEM, stream>>>(ea, res, o, eao, rp[lv], lcols[lv],
                                                        lvals[lv], Wp, b, nullptr, nullptr,
                                                        nullptr, mask1, acc, n);
    };
    // dense/avg layer (rank-1 avg term folded from accin via Wb)
    auto avg = [&](const ushort* ea, const float* res, float* o, ushort* eao,
                   const ushort* Wp, const float* b, const float* accin, const float* Wb,
                   float* accOut, int n) {
        layer_mfma<false><<<n / NR, 256, 0, stream>>>(ea, res, o, eao, nullptr, nullptr,
                                                      nullptr, Wp, b, accin, Wb, DEN,
                                                      mask1, accOut, n);
    };

    const size_t WSZ = 256 * 128;   // fp32 W stride per sub-layer
    const size_t PSZ = 2 * 16384;   // packed bf16 stride per sub-layer

    // ---- global branch ----
    conv1_kernel<<<(N * F) / 256, 256, 0, stream>>>(inputs, gW1, gb1, BUF0, EB0, N);
    lap(EB0, nullptr, BUF1, EB1, 3, Pd + 0 * PSZ, gdb + 0 * 128, nullptr, 16384);
    lap(EB1, BUF0, BUF2, nullptr, 3, Pd + 1 * PSZ, gdb + 1 * 128, nullptr, 16384);
    pool_kernel<<<(8192 * F) / 256, 256, 0, stream>>>(BUF2, D8, ED8, 8192);
    lap(ED8, nullptr, BUF1, EB1, 2, Pd + 2 * PSZ, gdb + 2 * 128, nullptr, 8192);
    lap(EB1, D8, BUF2, nullptr, 2, Pd + 3 * PSZ, gdb + 3 * 128, nullptr, 8192);
    pool_kernel<<<(4096 * F) / 256, 256, 0, stream>>>(BUF2, D4, ED4, 4096);
    lap(ED4, nullptr, BUF1, EB1, 1, Pd + 4 * PSZ, gdb + 4 * 128, nullptr, 4096);
    lap(EB1, D4, BUF2, nullptr, 1, Pd + 5 * PSZ, gdb + 5 * 128, nullptr, 4096);
    pool_kernel<<<(2048 * F) / 256, 256, 0, stream>>>(BUF2, D2, ED2, 2048);
    lap(ED2, nullptr, BUF1, EB1, 0, Pl + 0 * PSZ, glb + 0 * 128, nullptr, 2048);
    lap(EB1, D2, BUF2, nullptr, 0, Pl + 1 * PSZ, glb + 1 * 128, nullptr, 2048);
    upadd_kernel<<<(4096 * F) / 256, 256, 0, stream>>>(BUF2, D4, BUF1, EB1, 4096);
    lap(EB1, nullptr, BUF2, EB2, 1, Pu + 0 * PSZ, gub + 0 * 128, nullptr, 4096);
    lap(EB2, BUF1, D4, nullptr, 1, Pu + 1 * PSZ, gub + 1 * 128, nullptr, 4096);
    upadd_kernel<<<(8192 * F) / 256, 256, 0, stream>>>(D4, D8, BUF1, EB1, 8192);
    lap(EB1, nullptr, BUF2, EB2, 2, Pu + 2 * PSZ, gub + 2 * 128, nullptr, 8192);
    lap(EB2, BUF1, D8, nullptr, 2, Pu + 3 * PSZ, gub + 3 * 128, nullptr, 8192);
    upadd_kernel<<<(N * F) / 256, 256, 0, stream>>>(D8, BUF0, BUF1, EB1, N);
    lap(EB1, nullptr, BUF2, EB2, 3, Pu + 4 * PSZ, gub + 4 * 128, nullptr, N);
    lap(EB2, BUF1, BUF0, EB0, 3, Pu + 5 * PSZ, gub + 5 * 128, nullptr, N);
    // XG = BUF0 / EB0

    // ---- local branch ----
    conv1_kernel<<<(N * F) / 256, 256, 0, stream>>>(inputs, lW1, lb1, BUF1, EB1, N);
    for (int i = 0; i < 15; ++i) {
        const ushort* P = Pr + (size_t)(i * 2) * PSZ;
        const float* Wf = lrW + (size_t)i * 2 * WSZ;
        const float* b = lrb + (size_t)i * 2 * 128;
        if ((i & 1) == 0) {   // lap block on L
            lap(EB1, nullptr, BUF2, EB2, 4, P, b, nullptr, N);
            float* slot = (i <= 12) ? (ACC + i * 128) : nullptr;  // feeds avg block i+1
            lap(EB2, BUF1, BUF1, EB1, 4, P + PSZ, b + 128, slot, N);
        } else {              // avg block: rank-1 term folded in-kernel
            avg(EB1, nullptr, BUF2, EB2, P, b,
                ACC + (i - 1) * 128, Wf + F * F, ACC + i * 128, N);
            avg(EB2, BUF1, BUF1, EB1, P + PSZ, b + 128,
                ACC + i * 128, Wf + WSZ + F * F, nullptr, N);
        }
    }

    final_kernel<<<N / 2, 256, 0, stream>>>(EB0, EB1, inputs, gW2, gb2, lW2, lb2, out, N);
}

// Round 5
// 1036.643 us; speedup vs baseline: 3.7857x; 1.2156x over previous
//
#include <hip/hip_runtime.h>

#define F 128
#define SPAD 136      // LDS stride (ushorts) for S tile: 272 B = 17*16B
#define NR 32         // rows per block

typedef __attribute__((ext_vector_type(8))) short short8;
typedef __attribute__((ext_vector_type(16))) float f32x16;

__device__ __forceinline__ float elu_f(float x) {
    return x > 0.f ? x : __expf(x) - 1.f;
}
__device__ __forceinline__ ushort f2bf(float x) {   // fp32 -> bf16 RNE
    unsigned u = __float_as_uint(x);
    u = (u + 0x7FFFu + ((u >> 16) & 1u)) >> 16;
    return (ushort)u;
}
__device__ __forceinline__ float bf2f(ushort u) {
    return __uint_as_float((unsigned)u << 16);
}
__device__ __forceinline__ void bfma8(float* a, float v, short8 u) {
#pragma unroll
    for (int i = 0; i < 8; ++i) a[i] += v * bf2f((ushort)u[i]);
}

// rp[r] = lower_bound(rows, r) for r in [0, n]
__global__ void rowptr_kernel(const int* __restrict__ rows, int e, int n, int* __restrict__ rp) {
    int r = blockIdx.x * blockDim.x + threadIdx.x;
    if (r > n) return;
    int lo = 0, hi = e;
    while (lo < hi) { int mid = (lo + hi) >> 1; if (rows[mid] < r) lo = mid + 1; else hi = mid; }
    rp[r] = lo;
}

__global__ void denom_kernel(const float* __restrict__ mask, int n, float* __restrict__ denom) {
    __shared__ float red[256];
    float s = 0.f;
    for (int i = threadIdx.x; i < n; i += 256) s += mask[i];
    red[threadIdx.x] = s;
    __syncthreads();
    for (int st = 128; st > 0; st >>= 1) {
        if (threadIdx.x < st) red[threadIdx.x] += red[threadIdx.x + st];
        __syncthreads();
    }
    if (threadIdx.x == 0) denom[0] = red[0];
}

// out[r][c] = in[r]@W + b; ea = bf16(elu(out))
__global__ void conv1_kernel(const float* __restrict__ in, const float* __restrict__ W,
                             const float* __restrict__ b, float* __restrict__ out,
                             ushort* __restrict__ ea, int n) {
    int id = blockIdx.x * 256 + threadIdx.x;
    if (id >= n * F) return;
    int r = id >> 7, c = id & 127;
    float o = in[r * 3 + 0] * W[c] + in[r * 3 + 1] * W[F + c] + in[r * 3 + 2] * W[2 * F + c] + b[c];
    out[id] = o;
    ea[id] = f2bf(elu_f(o));
}

__global__ void pool_kernel(const float* __restrict__ in, float* __restrict__ out,
                            ushort* __restrict__ ea, int nout) {
    int id = blockIdx.x * 256 + threadIdx.x;
    if (id >= nout * F) return;
    int r = id >> 7, c = id & 127;
    float o = fmaxf(in[(2 * r) * F + c], in[(2 * r + 1) * F + c]);
    out[id] = o;
    ea[id] = f2bf(elu_f(o));
}

// out[r] = low[r/2] + skip[r]; ea = bf16(elu(out))
__global__ void upadd_kernel(const float* __restrict__ low, const float* __restrict__ skip,
                             float* __restrict__ out, ushort* __restrict__ ea, int nout) {
    int id = blockIdx.x * 256 + threadIdx.x;
    if (id >= nout * F) return;
    int r = id >> 7, c = id & 127;
    float o = low[(r >> 1) * F + c] + skip[id];
    out[id] = o;
    ea[id] = f2bf(elu_f(o));
}

// Pack one 128x128 fp32 W-half into 32x32x16 B-frag order, bf16.
// Coalesced linear read -> LDS scatter -> coalesced dump (old version gathered
// with stride-512B reads: 64 cache lines per wave-load).
__global__ void pack_kernel(const float* __restrict__ W, ushort* __restrict__ Wp) {
    __shared__ ushort tile[16384];
    const float* src = W + (size_t)blockIdx.x * 16384;
    ushort* dst = Wp + (size_t)blockIdx.x * 16384;
    for (int idx = threadIdx.x; idx < 16384; idx += 256) {
        int k = idx >> 7, nn = idx & 127;
        int k0 = k >> 4, rk = k & 15, j = rk & 7, lh = rk >> 3;
        int n0 = nn >> 5, ll = nn & 31;
        int frag = k0 * 4 + n0, lane = lh * 32 + ll;
        tile[(frag * 64 + lane) * 8 + j] = f2bf(src[idx]);
    }
    __syncthreads();
    const unsigned long long* ts = (const unsigned long long*)tile;
    unsigned long long* td = (unsigned long long*)dst;
    for (int i = threadIdx.x; i < 4096; i += 256) td[i] = ts[i];
}

// One resnet layer via MFMA, bf16-elu activation mirror (EA) in/out.
// LAP=true : OUT = [eluA, spmm(eluA)] @ W(256x128 packed) + bias (+RES)
// LAP=false: OUT = eluA @ W_top + bias (+RES); avg term folded via accin/Wb/den.
// EAOUT != nullptr: EAOUT = bf16(elu(OUT)).  accout != nullptr: accout[c] += sum elu(OUT)*mask.
template<bool LAP>
__global__ __launch_bounds__(256)
void layer_mfma(const ushort* __restrict__ EA, const float* RES,
                float* __restrict__ OUT, ushort* EAOUT,
                const int* __restrict__ rowptr, const int* __restrict__ cols,
                const float* __restrict__ vals,
                const ushort* __restrict__ Wp, const float* __restrict__ bias,
                const float* accin, const float* __restrict__ Wb, const float* den,
                const float* __restrict__ mask, float* accout, int n) {
    extern __shared__ ushort SS[];     // LAP: NR x SPAD bf16 spmm tile
    const int t = threadIdx.x;
    const int rbase = blockIdx.x * NR;
    const int w = t >> 6, l = t & 63, m = l & 31, kh = l >> 5;
    const int col = w * 32 + m;

    // preload dense-half A-fragments (in flight through the gather phase)
    short8 afrag[8];
    {
        const ushort* ear = EA + (size_t)(rbase + m) * F + kh * 8;
#pragma unroll
        for (int ki = 0; ki < 8; ++ki)
            afrag[ki] = *(const short8*)(ear + ki * 16);
    }

    if constexpr (LAP) {
        // gather: one row per 8-lane group (32 concurrent rows/block),
        // lane owns 32B of the row; edge loop unrolled x4 -> 8 loads in flight.
        const int grp = t >> 3;        // 0..31 = local row
        const int l8 = t & 7;
        const short8* EA8 = (const short8*)EA;   // 16 short8 per row
        const int chunk = l8 * 2;
        int row = rbase + grp;
        int e0 = rowptr[row], e1 = rowptr[row + 1];
        float acc0[16], acc1[16];
#pragma unroll
        for (int i = 0; i < 16; ++i) { acc0[i] = 0.f; acc1[i] = 0.f; }
        int e = e0;
        for (; e + 4 <= e1; e += 4) {
            int c0 = cols[e + 0], c1 = cols[e + 1], c2 = cols[e + 2], c3 = cols[e + 3];
            float v0 = vals[e + 0], v1 = vals[e + 1], v2 = vals[e + 2], v3 = vals[e + 3];
            short8 u0a = EA8[(size_t)c0 * 16 + chunk], u0b = EA8[(size_t)c0 * 16 + chunk + 1];
            short8 u1a = EA8[(size_t)c1 * 16 + chunk], u1b = EA8[(size_t)c1 * 16 + chunk + 1];
            short8 u2a = EA8[(size_t)c2 * 16 + chunk], u2b = EA8[(size_t)c2 * 16 + chunk + 1];
            short8 u3a = EA8[(size_t)c3 * 16 + chunk], u3b = EA8[(size_t)c3 * 16 + chunk + 1];
            bfma8(acc0, v0, u0a); bfma8(acc0 + 8, v0, u0b);
            bfma8(acc1, v1, u1a); bfma8(acc1 + 8, v1, u1b);
            bfma8(acc0, v2, u2a); bfma8(acc0 + 8, v2, u2b);
            bfma8(acc1, v3, u3a); bfma8(acc1 + 8, v3, u3b);
        }
        for (; e < e1; ++e) {
            int c = cols[e];
            float v = vals[e];
            short8 ua = EA8[(size_t)c * 16 + chunk], ub = EA8[(size_t)c * 16 + chunk + 1];
            bfma8(acc0, v, ua); bfma8(acc0 + 8, v, ub);
        }
        short8 s0, s1;
#pragma unroll
        for (int i = 0; i < 8; ++i) {
            s0[i] = (short)f2bf(acc0[i] + acc1[i]);
            s1[i] = (short)f2bf(acc0[8 + i] + acc1[8 + i]);
        }
        *(short8*)(&SS[grp * SPAD + l8 * 16]) = s0;
        *(short8*)(&SS[grp * SPAD + l8 * 16 + 8]) = s1;
        __syncthreads();
    }

    // per-col bias (+ folded rank-1 avg term for avg layers)
    float bv = bias[col];
    if (accin) {
        float inv = 1.f / den[0];
#pragma unroll 4
        for (int k = 0; k < F; ++k) bv += (accin[k] * inv) * Wb[k * F + col];
    }

    f32x16 acc;
#pragma unroll
    for (int i = 0; i < 16; ++i) acc[i] = 0.f;

#pragma unroll
    for (int ki = 0; ki < 8; ++ki) {
        short8 b = *(const short8*)(Wp + (size_t)(((ki * 4 + w) * 64 + l) * 8));
        acc = __builtin_amdgcn_mfma_f32_32x32x16_bf16(afrag[ki], b, acc, 0, 0, 0);
    }
    if constexpr (LAP) {
        const ushort* ssr = &SS[m * SPAD + kh * 8];
#pragma unroll
        for (int ki = 0; ki < 8; ++ki) {
            short8 a = *(const short8*)(ssr + ki * 16);
            short8 b = *(const short8*)(Wp + 16384 + (size_t)(((ki * 4 + w) * 64 + l) * 8));
            acc = __builtin_amdgcn_mfma_f32_32x32x16_bf16(a, b, acc, 0, 0, 0);
        }
    }

    float outv[16];
#pragma unroll
    for (int reg = 0; reg < 16; ++reg) {
        int r = (reg & 3) + 8 * (reg >> 2) + 4 * kh;
        size_t rg = (size_t)(rbase + r);
        float v = acc[reg] + bv;
        if (RES) v += RES[rg * F + col];
        OUT[rg * F + col] = v;
        outv[reg] = v;
    }
    if (EAOUT || accout) {
        float ev[16];
#pragma unroll
        for (int reg = 0; reg < 16; ++reg) ev[reg] = elu_f(outv[reg]);
        if (EAOUT) {
#pragma unroll
            for (int reg = 0; reg < 16; ++reg) {
                int r = (reg & 3) + 8 * (reg >> 2) + 4 * kh;
                EAOUT[(size_t)(rbase + r) * F + col] = f2bf(ev[reg]);
            }
        }
        if (accout) {
            float p = 0.f;
#pragma unroll
            for (int reg = 0; reg < 16; ++reg) {
                int r = (reg & 3) + 8 * (reg >> 2) + 4 * kh;
                p += ev[reg] * mask[rbase + r];
            }
            p += __shfl_xor(p, 32, 64);
            if (l < 32) atomicAdd(accout + col, p);
        }
    }
}

// reads bf16-elu mirrors of XG and Y directly
__global__ void final_kernel(const ushort* __restrict__ EAX, const ushort* __restrict__ EAY,
                             const float* __restrict__ inputs,
                             const float* __restrict__ gW2, const float* __restrict__ gb2,
                             const float* __restrict__ lW2, const float* __restrict__ lb2,
                             float* __restrict__ out, int n) {
    __shared__ float sg_s[4], sl_s[4];
    int t = threadIdx.x;
    int rh = t >> 7, f = t & 127;
    size_t row = (size_t)blockIdx.x * 2 + rh;
    float pg = bf2f(EAX[row * F + f]) * gW2[f * 2 + 0];
    float pl = bf2f(EAY[row * F + f]) * lW2[f];
#pragma unroll
    for (int o = 32; o > 0; o >>= 1) {
        pg += __shfl_down(pg, o, 64);
        pl += __shfl_down(pl, o, 64);
    }
    int wave = t >> 6;
    if ((t & 63) == 0) { sg_s[wave] = pg; sl_s[wave] = pl; }
    __syncthreads();
    if (t < 2) {
        size_t r = (size_t)blockIdx.x * 2 + t;
        float sg = sg_s[t * 2] + sg_s[t * 2 + 1] + gb2[0] + inputs[r * 3 + 0];
        float sl = sl_s[t * 2] + sl_s[t * 2 + 1] + lb2[0] + inputs[r * 3 + 0];
        float wgt = 1.f / (1.f + __expf(-sg));
        out[r] = sg;
        out[n + r] = sl;
        out[2 * n + r] = wgt * sg + (1.f - wgt) * sl;
    }
}

extern "C" void kernel_launch(void* const* d_in, const int* in_sizes, int n_in,
                              void* d_out, int out_size, void* d_ws, size_t ws_size,
                              hipStream_t stream) {
    (void)in_sizes; (void)n_in; (void)out_size; (void)ws_size;
    const float* inputs = (const float*)d_in[0];
    const float* mask1  = (const float*)d_in[2];
    const int*   lrows[5] = {(const int*)d_in[3], (const int*)d_in[6], (const int*)d_in[9],
                             (const int*)d_in[12], (const int*)d_in[15]};
    const int*   lcols[5] = {(const int*)d_in[4], (const int*)d_in[7], (const int*)d_in[10],
                             (const int*)d_in[13], (const int*)d_in[16]};
    const float* lvals[5] = {(const float*)d_in[5], (const float*)d_in[8], (const float*)d_in[11],
                             (const float*)d_in[14], (const float*)d_in[17]};
    const float* gW1 = (const float*)d_in[18];
    const float* gb1 = (const float*)d_in[19];
    const float* gdW = (const float*)d_in[20];
    const float* gdb = (const float*)d_in[21];
    const float* glW = (const float*)d_in[22];
    const float* glb = (const float*)d_in[23];
    const float* guW = (const float*)d_in[24];
    const float* gub = (const float*)d_in[25];
    const float* gW2 = (const float*)d_in[26];
    const float* gb2 = (const float*)d_in[27];
    const float* lW1 = (const float*)d_in[28];
    const float* lb1 = (const float*)d_in[29];
    const float* lrW = (const float*)d_in[30];
    const float* lrb = (const float*)d_in[31];
    const float* lW2 = (const float*)d_in[32];
    const float* lb2 = (const float*)d_in[33];
    float* out = (float*)d_out;

    const int N = 16384;
    const int nlev[5] = {2048, 4096, 8192, 16384, 16384};
    const int elev[5] = {16384, 32768, 65536, 131072, 131072};

    char* ws = (char*)d_ws;
    size_t off = 0;
    auto alloc = [&](size_t bytes) -> char* {
        char* p = ws + off;
        off = (off + bytes + 255) & ~(size_t)255;
        return p;
    };
    float* BUF0 = (float*)alloc((size_t)N * F * 4);
    float* BUF1 = (float*)alloc((size_t)N * F * 4);
    float* BUF2 = (float*)alloc((size_t)N * F * 4);
    float* D8   = (float*)alloc((size_t)8192 * F * 4);
    float* D4   = (float*)alloc((size_t)4096 * F * 4);
    float* D2   = (float*)alloc((size_t)2048 * F * 4);
    // bf16 elu mirrors
    ushort* EB0 = (ushort*)alloc((size_t)N * F * 2);
    ushort* EB1 = (ushort*)alloc((size_t)N * F * 2);
    ushort* EB2 = (ushort*)alloc((size_t)N * F * 2);
    ushort* ED8 = (ushort*)alloc((size_t)8192 * F * 2);
    ushort* ED4 = (ushort*)alloc((size_t)4096 * F * 2);
    ushort* ED2 = (ushort*)alloc((size_t)2048 * F * 2);
    int* rp[5];
    for (int i = 0; i < 5; ++i) rp[i] = (int*)alloc((size_t)(nlev[i] + 1) * 4);
    float* ACC = (float*)alloc(14 * 128 * 4);
    float* DEN = (float*)alloc(4);
    ushort* Pd = (ushort*)alloc((size_t)12 * 16384 * 2);
    ushort* Pl = (ushort*)alloc((size_t)4  * 16384 * 2);
    ushort* Pu = (ushort*)alloc((size_t)12 * 16384 * 2);
    ushort* Pr = (ushort*)alloc((size_t)60 * 16384 * 2);

    hipMemsetAsync(ACC, 0, 14 * 128 * 4, stream);
    for (int i = 0; i < 5; ++i)
        rowptr_kernel<<<(nlev[i] + 256) / 256, 256, 0, stream>>>(lrows[i], elev[i], nlev[i], rp[i]);
    denom_kernel<<<1, 256, 0, stream>>>(mask1, N, DEN);
    pack_kernel<<<12, 256, 0, stream>>>(gdW, Pd);
    pack_kernel<<<4,  256, 0, stream>>>(glW, Pl);
    pack_kernel<<<12, 256, 0, stream>>>(guW, Pu);
    pack_kernel<<<60, 256, 0, stream>>>(lrW, Pr);

    const size_t SMEM = (size_t)NR * SPAD * 2;

    // lap layer
    auto lap = [&](const ushort* ea, const float* res, float* o, ushort* eao, int lv,
                   const ushort* Wp, const float* b, float* acc, int n) {
        layer_mfma<true><<<n / NR, 256, SMEM, stream>>>(ea, res, o, eao, rp[lv], lcols[lv],
                                                        lvals[lv], Wp, b, nullptr, nullptr,
                                                        nullptr, mask1, acc, n);
    };
    // dense/avg layer (rank-1 avg term folded from accin via Wb)
    auto avg = [&](const ushort* ea, const float* res, float* o, ushort* eao,
                   const ushort* Wp, const float* b, const float* accin, const float* Wb,
                   float* accOut, int n) {
        layer_mfma<false><<<n / NR, 256, 0, stream>>>(ea, res, o, eao, nullptr, nullptr,
                                                      nullptr, Wp, b, accin, Wb, DEN,
                                                      mask1, accOut, n);
    };

    const size_t WSZ = 256 * 128;   // fp32 W stride per sub-layer
    const size_t PSZ = 2 * 16384;   // packed bf16 stride per sub-layer

    // ---- global branch ----
    conv1_kernel<<<(N * F) / 256, 256, 0, stream>>>(inputs, gW1, gb1, BUF0, EB0, N);
    lap(EB0, nullptr, BUF1, EB1, 3, Pd + 0 * PSZ, gdb + 0 * 128, nullptr, 16384);
    lap(EB1, BUF0, BUF2, nullptr, 3, Pd + 1 * PSZ, gdb + 1 * 128, nullptr, 16384);
    pool_kernel<<<(8192 * F) / 256, 256, 0, stream>>>(BUF2, D8, ED8, 8192);
    lap(ED8, nullptr, BUF1, EB1, 2, Pd + 2 * PSZ, gdb + 2 * 128, nullptr, 8192);
    lap(EB1, D8, BUF2, nullptr, 2, Pd + 3 * PSZ, gdb + 3 * 128, nullptr, 8192);
    pool_kernel<<<(4096 * F) / 256, 256, 0, stream>>>(BUF2, D4, ED4, 4096);
    lap(ED4, nullptr, BUF1, EB1, 1, Pd + 4 * PSZ, gdb + 4 * 128, nullptr, 4096);
    lap(EB1, D4, BUF2, nullptr, 1, Pd + 5 * PSZ, gdb + 5 * 128, nullptr, 4096);
    pool_kernel<<<(2048 * F) / 256, 256, 0, stream>>>(BUF2, D2, ED2, 2048);
    lap(ED2, nullptr, BUF1, EB1, 0, Pl + 0 * PSZ, glb + 0 * 128, nullptr, 2048);
    lap(EB1, D2, BUF2, nullptr, 0, Pl + 1 * PSZ, glb + 1 * 128, nullptr, 2048);
    upadd_kernel<<<(4096 * F) / 256, 256, 0, stream>>>(BUF2, D4, BUF1, EB1, 4096);
    lap(EB1, nullptr, BUF2, EB2, 1, Pu + 0 * PSZ, gub + 0 * 128, nullptr, 4096);
    lap(EB2, BUF1, D4, nullptr, 1, Pu + 1 * PSZ, gub + 1 * 128, nullptr, 4096);
    upadd_kernel<<<(8192 * F) / 256, 256, 0, stream>>>(D4, D8, BUF1, EB1, 8192);
    lap(EB1, nullptr, BUF2, EB2, 2, Pu + 2 * PSZ, gub + 2 * 128, nullptr, 8192);
    lap(EB2, BUF1, D8, nullptr, 2, Pu + 3 * PSZ, gub + 3 * 128, nullptr, 8192);
    upadd_kernel<<<(N * F) / 256, 256, 0, stream>>>(D8, BUF0, BUF1, EB1, N);
    lap(EB1, nullptr, BUF2, EB2, 3, Pu + 4 * PSZ, gub + 4 * 128, nullptr, N);
    lap(EB2, BUF1, BUF0, EB0, 3, Pu + 5 * PSZ, gub + 5 * 128, nullptr, N);
    // XG = BUF0 / EB0

    // ---- local branch ----
    conv1_kernel<<<(N * F) / 256, 256, 0, stream>>>(inputs, lW1, lb1, BUF1, EB1, N);
    for (int i = 0; i < 15; ++i) {
        const ushort* P = Pr + (size_t)(i * 2) * PSZ;
        const float* Wf = lrW + (size_t)i * 2 * WSZ;
        const float* b = lrb + (size_t)i * 2 * 128;
        if ((i & 1) == 0) {   // lap block on L
            lap(EB1, nullptr, BUF2, EB2, 4, P, b, nullptr, N);
            float* slot = (i <= 12) ? (ACC + i * 128) : nullptr;  // feeds avg block i+1
            lap(EB2, BUF1, BUF1, EB1, 4, P + PSZ, b + 128, slot, N);
        } else {              // avg block: rank-1 term folded in-kernel
            avg(EB1, nullptr, BUF2, EB2, P, b,
                ACC + (i - 1) * 128, Wf + F * F, ACC + i * 128, N);
            avg(EB2, BUF1, BUF1, EB1, P + PSZ, b + 128,
                ACC + i * 128, Wf + WSZ + F * F, nullptr, N);
        }
    }

    final_kernel<<<N / 2, 256, 0, stream>>>(EB0, EB1, inputs, gW2, gb2, lW2, lb2, out, N);
}

// Round 6
// 844.172 us; speedup vs baseline: 4.6488x; 1.2280x over previous
//
#include <hip/hip_runtime.h>

#define F 128
#define SPAD 136      // LDS stride (ushorts) for S tile
#define NR 32         // rows per block

typedef __attribute__((ext_vector_type(8))) short short8;
typedef __attribute__((ext_vector_type(16))) float f32x16;
typedef unsigned long long ull;

__device__ __forceinline__ float elu_f(float x) {
    return x > 0.f ? x : __expf(x) - 1.f;
}
__device__ __forceinline__ ushort f2bf(float x) {   // fp32 -> bf16 RNE
    unsigned u = __float_as_uint(x);
    u = (u + 0x7FFFu + ((u >> 16) & 1u)) >> 16;
    return (ushort)u;
}
__device__ __forceinline__ float bf2f(ushort u) {
    return __uint_as_float((unsigned)u << 16);
}
__device__ __forceinline__ void bfma8(float* a, float v, short8 u) {
#pragma unroll
    for (int i = 0; i < 8; ++i) a[i] += v * bf2f((ushort)u[i]);
}

// ---------------- setup: weight pack + rowptr + denom + ACC zero ----------------
struct SetupArgs {
    const float* ws0; const float* ws1; const float* ws2; const float* ws3;
    ushort* wd0; ushort* wd1; ushort* wd2; ushort* wd3;
    const int* rows0; const int* rows1; const int* rows2; const int* rows3; const int* rows4;
    int* rp0; int* rp1; int* rp2; int* rp3; int* rp4;
    const float* mask; float* den; float* acc;
};

__global__ __launch_bounds__(256) void setup_kernel(SetupArgs s) {
    __shared__ ushort tile[16384];
    int b = blockIdx.x, t = threadIdx.x;
    if (b < 88) {
        // pack one 128x128 fp32 half into 32x32x16 B-frag order (coalesced read)
        const float* src; ushort* dst; int lb;
        if (b < 12)      { src = s.ws0; dst = s.wd0; lb = b; }
        else if (b < 16) { src = s.ws1; dst = s.wd1; lb = b - 12; }
        else if (b < 28) { src = s.ws2; dst = s.wd2; lb = b - 16; }
        else             { src = s.ws3; dst = s.wd3; lb = b - 28; }
        src += (size_t)lb * 16384; dst += (size_t)lb * 16384;
        for (int idx = t; idx < 16384; idx += 256) {
            int k = idx >> 7, nn = idx & 127;
            int k0 = k >> 4, rk = k & 15, j = rk & 7, lh = rk >> 3;
            int n0 = nn >> 5, ll = nn & 31;
            tile[((k0 * 4 + n0) * 64 + lh * 32 + ll) * 8 + j] = f2bf(src[idx]);
        }
        __syncthreads();
        ull* td = (ull*)dst; const ull* ts = (const ull*)tile;
        for (int i = t; i < 4096; i += 256) td[i] = ts[i];
    } else if (b < 273) {
        int tid = (b - 88) * 256 + t;
        const int ns[5] = {2048, 4096, 8192, 16384, 16384};
        const int es[5] = {16384, 32768, 65536, 131072, 131072};
        const int* rowsA[5] = {s.rows0, s.rows1, s.rows2, s.rows3, s.rows4};
        int* rpA[5] = {s.rp0, s.rp1, s.rp2, s.rp3, s.rp4};
        int base = 0;
        for (int lv = 0; lv < 5; ++lv) {
            int cnt = ns[lv] + 1;
            if (tid < base + cnt) {
                int r = tid - base;
                const int* rows = rowsA[lv]; int e = es[lv];
                int lo = 0, hi = e;
                while (lo < hi) { int mid = (lo + hi) >> 1; if (rows[mid] < r) lo = mid + 1; else hi = mid; }
                rpA[lv][r] = lo;
                return;
            }
            base += cnt;
        }
    } else {
        __shared__ float red[256];
        float ssum = 0.f;
        for (int i = t; i < 16384; i += 256) ssum += s.mask[i];
        red[t] = ssum; __syncthreads();
        for (int st = 128; st > 0; st >>= 1) { if (t < st) red[t] += red[t + st]; __syncthreads(); }
        if (t == 0) s.den[0] = red[0];
        for (int i = t; i < 1792; i += 256) s.acc[i] = 0.f;
    }
}

// both conv1s in one pass over inputs
__global__ void conv1_dual(const float* __restrict__ in,
                           const float* __restrict__ Wg, const float* __restrict__ bg,
                           const float* __restrict__ Wl, const float* __restrict__ bl,
                           float* __restrict__ og, ushort* __restrict__ eg,
                           float* __restrict__ ol, ushort* __restrict__ el, int n) {
    int id = blockIdx.x * 256 + threadIdx.x;
    if (id >= n * F) return;
    int r = id >> 7, c = id & 127;
    float x0 = in[r * 3 + 0], x1 = in[r * 3 + 1], x2 = in[r * 3 + 2];
    float g = x0 * Wg[c] + x1 * Wg[F + c] + x2 * Wg[2 * F + c] + bg[c];
    float lo = x0 * Wl[c] + x1 * Wl[F + c] + x2 * Wl[2 * F + c] + bl[c];
    og[id] = g;  eg[id] = f2bf(elu_f(g));
    ol[id] = lo; el[id] = f2bf(elu_f(lo));
}

// ---------------- unified layer ----------------
struct LArgs {
    const ushort* EA; const float* RES; float* OUT; ushort* EAOUT;
    const int* rowptr; const int* cols; const float* vals;
    const ushort* Wp; const float* bias;
    const float* accin; const float* Wb; const float* den;
    const float* mask; float* accout;
    float* EO; ushort* EE; const float* SKIP;   // fused epilogue buffers
    int epi;  // 0 none, 1 maxpool2 (n/2), 2 upadd (2n with SKIP)
};

__device__ __forceinline__ void layer_body(const LArgs& a, int blk, ushort* SS) {
    const int t = threadIdx.x;
    const int rbase = blk * NR;
    const int w = t >> 6, l = t & 63, m = l & 31, kh = l >> 5;
    const int col = w * 32 + m;
    const bool lap = (a.rowptr != nullptr);

    // dense-half A-fragments straight from EA global (frag-exact layout)
    short8 afrag[8];
    {
        const ushort* ear = a.EA + (size_t)(rbase + m) * F + kh * 8;
#pragma unroll
        for (int ki = 0; ki < 8; ++ki) afrag[ki] = *(const short8*)(ear + ki * 16);
    }

    if (lap) {
        // one row per 8-lane group, 32 concurrent rows/block, x4 edge unroll
        const int grp = t >> 3, l8 = t & 7;
        const short8* EA8 = (const short8*)a.EA;
        const int chunk = l8 * 2;
        int row = rbase + grp;
        int e0 = a.rowptr[row], e1 = a.rowptr[row + 1];
        float acc0[16], acc1[16];
#pragma unroll
        for (int i = 0; i < 16; ++i) { acc0[i] = 0.f; acc1[i] = 0.f; }
        int e = e0;
        for (; e + 4 <= e1; e += 4) {
            int c0 = a.cols[e + 0], c1 = a.cols[e + 1], c2 = a.cols[e + 2], c3 = a.cols[e + 3];
            float v0 = a.vals[e + 0], v1 = a.vals[e + 1], v2 = a.vals[e + 2], v3 = a.vals[e + 3];
            short8 u0a = EA8[(size_t)c0 * 16 + chunk], u0b = EA8[(size_t)c0 * 16 + chunk + 1];
            short8 u1a = EA8[(size_t)c1 * 16 + chunk], u1b = EA8[(size_t)c1 * 16 + chunk + 1];
            short8 u2a = EA8[(size_t)c2 * 16 + chunk], u2b = EA8[(size_t)c2 * 16 + chunk + 1];
            short8 u3a = EA8[(size_t)c3 * 16 + chunk], u3b = EA8[(size_t)c3 * 16 + chunk + 1];
            bfma8(acc0, v0, u0a); bfma8(acc0 + 8, v0, u0b);
            bfma8(acc1, v1, u1a); bfma8(acc1 + 8, v1, u1b);
            bfma8(acc0, v2, u2a); bfma8(acc0 + 8, v2, u2b);
            bfma8(acc1, v3, u3a); bfma8(acc1 + 8, v3, u3b);
        }
        for (; e < e1; ++e) {
            int c = a.cols[e];
            float v = a.vals[e];
            short8 ua = EA8[(size_t)c * 16 + chunk], ub = EA8[(size_t)c * 16 + chunk + 1];
            bfma8(acc0, v, ua); bfma8(acc0 + 8, v, ub);
        }
        short8 s0, s1;
#pragma unroll
        for (int i = 0; i < 8; ++i) {
            s0[i] = (short)f2bf(acc0[i] + acc1[i]);
            s1[i] = (short)f2bf(acc0[8 + i] + acc1[8 + i]);
        }
        *(short8*)(&SS[grp * SPAD + l8 * 16]) = s0;
        *(short8*)(&SS[grp * SPAD + l8 * 16 + 8]) = s1;
        __syncthreads();
    }

    // per-col bias (+ folded rank-1 avg term)
    float bv = a.bias[col];
    if (a.accin) {
        float inv = 1.f / a.den[0];
#pragma unroll 4
        for (int k = 0; k < F; ++k) bv += (a.accin[k] * inv) * a.Wb[k * F + col];
    }

    f32x16 acc;
#pragma unroll
    for (int i = 0; i < 16; ++i) acc[i] = 0.f;
#pragma unroll
    for (int ki = 0; ki < 8; ++ki) {
        short8 b = *(const short8*)(a.Wp + (size_t)(((ki * 4 + w) * 64 + l) * 8));
        acc = __builtin_amdgcn_mfma_f32_32x32x16_bf16(afrag[ki], b, acc, 0, 0, 0);
    }
    if (lap) {
        const ushort* ssr = &SS[m * SPAD + kh * 8];
#pragma unroll
        for (int ki = 0; ki < 8; ++ki) {
            short8 aa = *(const short8*)(ssr + ki * 16);
            short8 b = *(const short8*)(a.Wp + 16384 + (size_t)(((ki * 4 + w) * 64 + l) * 8));
            acc = __builtin_amdgcn_mfma_f32_32x32x16_bf16(aa, b, acc, 0, 0, 0);
        }
    }

    float outv[16];
#pragma unroll
    for (int reg = 0; reg < 16; ++reg) {
        int r = (reg & 3) + 8 * (reg >> 2) + 4 * kh;
        size_t rg = (size_t)(rbase + r);
        float v = acc[reg] + bv;
        if (a.RES) v += a.RES[rg * F + col];
        outv[reg] = v;
        if (a.OUT) a.OUT[rg * F + col] = v;
        if (a.EAOUT) a.EAOUT[rg * F + col] = f2bf(elu_f(v));
    }
    if (a.accout) {
        float p = 0.f;
#pragma unroll
        for (int reg = 0; reg < 16; ++reg) {
            int r = (reg & 3) + 8 * (reg >> 2) + 4 * kh;
            p += elu_f(outv[reg]) * a.mask[rbase + r];
        }
        p += __shfl_xor(p, 32, 64);
        if (l < 32) atomicAdd(a.accout + col, p);
    }
    if (a.epi == 1) {          // fused maxpool2: pairs are lane-local
        int rb2 = rbase >> 1;
#pragma unroll
        for (int q = 0; q < 4; ++q)
#pragma unroll
            for (int e = 0; e < 2; ++e) {
                float pv = fmaxf(outv[q * 4 + e * 2], outv[q * 4 + e * 2 + 1]);
                size_t idx = (size_t)(rb2 + q * 4 + kh * 2 + e) * F + col;
                a.EO[idx] = pv;
                a.EE[idx] = f2bf(elu_f(pv));
            }
    } else if (a.epi == 2) {   // fused repeat2 + skip add
#pragma unroll
        for (int reg = 0; reg < 16; ++reg) {
            int r = (reg & 3) + 8 * (reg >> 2) + 4 * kh;
            size_t R0 = (size_t)(2 * (rbase + r)) * F + col;
            float v0 = outv[reg] + a.SKIP[R0];
            float v1 = outv[reg] + a.SKIP[R0 + F];
            a.EO[R0] = v0;     a.EO[R0 + F] = v1;
            a.EE[R0] = f2bf(elu_f(v0)); a.EE[R0 + F] = f2bf(elu_f(v1));
        }
    }
}

__global__ __launch_bounds__(256)
void dual_layer(LArgs A, LArgs B, int nA) {
    __shared__ ushort SS[NR * SPAD];
    bool isA = (int)blockIdx.x < nA;
    const LArgs& a = isA ? A : B;
    int blk = isA ? blockIdx.x : blockIdx.x - nA;
    layer_body(a, blk, SS);
}

__global__ void final_kernel(const ushort* __restrict__ EAX, const ushort* __restrict__ EAY,
                             const float* __restrict__ inputs,
                             const float* __restrict__ gW2, const float* __restrict__ gb2,
                             const float* __restrict__ lW2, const float* __restrict__ lb2,
                             float* __restrict__ out, int n) {
    __shared__ float sg_s[4], sl_s[4];
    int t = threadIdx.x;
    int rh = t >> 7, f = t & 127;
    size_t row = (size_t)blockIdx.x * 2 + rh;
    float pg = bf2f(EAX[row * F + f]) * gW2[f * 2 + 0];
    float pl = bf2f(EAY[row * F + f]) * lW2[f];
#pragma unroll
    for (int o = 32; o > 0; o >>= 1) {
        pg += __shfl_down(pg, o, 64);
        pl += __shfl_down(pl, o, 64);
    }
    int wave = t >> 6;
    if ((t & 63) == 0) { sg_s[wave] = pg; sl_s[wave] = pl; }
    __syncthreads();
    if (t < 2) {
        size_t r = (size_t)blockIdx.x * 2 + t;
        float sg = sg_s[t * 2] + sg_s[t * 2 + 1] + gb2[0] + inputs[r * 3 + 0];
        float sl = sl_s[t * 2] + sl_s[t * 2 + 1] + lb2[0] + inputs[r * 3 + 0];
        float wgt = 1.f / (1.f + __expf(-sg));
        out[r] = sg;
        out[n + r] = sl;
        out[2 * n + r] = wgt * sg + (1.f - wgt) * sl;
    }
}

extern "C" void kernel_launch(void* const* d_in, const int* in_sizes, int n_in,
                              void* d_out, int out_size, void* d_ws, size_t ws_size,
                              hipStream_t stream) {
    (void)in_sizes; (void)n_in; (void)out_size; (void)ws_size;
    const float* inputs = (const float*)d_in[0];
    const float* mask1  = (const float*)d_in[2];
    const int*   lrows[5] = {(const int*)d_in[3], (const int*)d_in[6], (const int*)d_in[9],
                             (const int*)d_in[12], (const int*)d_in[15]};
    const int*   lcols[5] = {(const int*)d_in[4], (const int*)d_in[7], (const int*)d_in[10],
                             (const int*)d_in[13], (const int*)d_in[16]};
    const float* lvals[5] = {(const float*)d_in[5], (const float*)d_in[8], (const float*)d_in[11],
                             (const float*)d_in[14], (const float*)d_in[17]};
    const float* gW1 = (const float*)d_in[18];
    const float* gb1 = (const float*)d_in[19];
    const float* gdW = (const float*)d_in[20];
    const float* gdb = (const float*)d_in[21];
    const float* glW = (const float*)d_in[22];
    const float* glb = (const float*)d_in[23];
    const float* guW = (const float*)d_in[24];
    const float* gub = (const float*)d_in[25];
    const float* gW2 = (const float*)d_in[26];
    const float* gb2 = (const float*)d_in[27];
    const float* lW1 = (const float*)d_in[28];
    const float* lb1 = (const float*)d_in[29];
    const float* lrW = (const float*)d_in[30];
    const float* lrb = (const float*)d_in[31];
    const float* lW2 = (const float*)d_in[32];
    const float* lb2 = (const float*)d_in[33];
    float* out = (float*)d_out;

    const int N = 16384;
    const int nlev[5] = {2048, 4096, 8192, 16384, 16384};

    char* ws = (char*)d_ws;
    size_t off = 0;
    auto alloc = [&](size_t bytes) -> char* {
        char* p = ws + off;
        off = (off + bytes + 255) & ~(size_t)255;
        return p;
    };
    // fp32
    float* BUF0 = (float*)alloc((size_t)N * F * 4);       // g conv1 out / down[-3] res
    float* GU   = (float*)alloc((size_t)N * F * 4);       // up-path carrier A
    float* G2   = (float*)alloc((size_t)N * F * 4);       // up-path carrier B
    float* D8   = (float*)alloc((size_t)8192 * F * 4);
    float* D4   = (float*)alloc((size_t)4096 * F * 4);
    float* D2   = (float*)alloc((size_t)2048 * F * 4);
    float* LB   = (float*)alloc((size_t)N * F * 4);       // local residual carrier
    // bf16 elu mirrors
    ushort* EB0 = (ushort*)alloc((size_t)N * F * 2);
    ushort* EG1 = (ushort*)alloc((size_t)N * F * 2);
    ushort* EG2 = (ushort*)alloc((size_t)N * F * 2);
    ushort* ED8 = (ushort*)alloc((size_t)8192 * F * 2);
    ushort* ED4 = (ushort*)alloc((size_t)4096 * F * 2);
    ushort* ED2 = (ushort*)alloc((size_t)2048 * F * 2);
    ushort* LE1 = (ushort*)alloc((size_t)N * F * 2);
    ushort* LE2 = (ushort*)alloc((size_t)N * F * 2);
    int* rp[5];
    for (int i = 0; i < 5; ++i) rp[i] = (int*)alloc((size_t)(nlev[i] + 1) * 4);
    float* ACC = (float*)alloc(14 * 128 * 4);
    float* DEN = (float*)alloc(4);
    ushort* Pd = (ushort*)alloc((size_t)12 * 16384 * 2);
    ushort* Pl = (ushort*)alloc((size_t)4  * 16384 * 2);
    ushort* Pu = (ushort*)alloc((size_t)12 * 16384 * 2);
    ushort* Pr = (ushort*)alloc((size_t)60 * 16384 * 2);

    // setup (pack + rowptr + denom + ACC zero), one dispatch
    SetupArgs sa;
    sa.ws0 = gdW; sa.ws1 = glW; sa.ws2 = guW; sa.ws3 = lrW;
    sa.wd0 = Pd;  sa.wd1 = Pl;  sa.wd2 = Pu;  sa.wd3 = Pr;
    sa.rows0 = lrows[0]; sa.rows1 = lrows[1]; sa.rows2 = lrows[2];
    sa.rows3 = lrows[3]; sa.rows4 = lrows[4];
    sa.rp0 = rp[0]; sa.rp1 = rp[1]; sa.rp2 = rp[2]; sa.rp3 = rp[3]; sa.rp4 = rp[4];
    sa.mask = mask1; sa.den = DEN; sa.acc = ACC;
    setup_kernel<<<274, 256, 0, stream>>>(sa);

    conv1_dual<<<8192, 256, 0, stream>>>(inputs, gW1, gb1, lW1, lb1, BUF0, EB0, LB, LE1, N);

    const size_t WSZ = 256 * 128;   // fp32 W stride per sub-layer
    const size_t PSZ = 2 * 16384;   // packed bf16 stride per sub-layer

    auto mkL = [&](const ushort* ea, const float* res, float* o, ushort* eao,
                   int lv, const ushort* wp, const float* bias, float* accout,
                   int epi, float* eo, ushort* ee, const float* skip,
                   const float* accin, const float* wb) {
        LArgs x;
        x.EA = ea; x.RES = res; x.OUT = o; x.EAOUT = eao;
        x.rowptr = (lv >= 0) ? rp[lv] : nullptr;
        x.cols = (lv >= 0) ? lcols[lv] : nullptr;
        x.vals = (lv >= 0) ? lvals[lv] : nullptr;
        x.Wp = wp; x.bias = bias;
        x.accin = accin; x.Wb = wb; x.den = DEN;
        x.mask = mask1; x.accout = accout;
        x.EO = eo; x.EE = ee; x.SKIP = skip; x.epi = epi;
        return x;
    };

    // ---- global branch: 14 steps (pool/upadd fused into sub2 epilogues) ----
    LArgs gs[14]; int gn[14];
    gs[0]  = mkL(EB0, 0, 0, EG1, 3, Pd + 0 * PSZ, gdb + 0,   0, 0, 0, 0, 0, 0, 0);  gn[0]  = 16384;
    gs[1]  = mkL(EG1, BUF0, 0, 0, 3, Pd + 1 * PSZ, gdb + 128, 0, 1, D8, ED8, 0, 0, 0); gn[1] = 16384;
    gs[2]  = mkL(ED8, 0, 0, EG1, 2, Pd + 2 * PSZ, gdb + 256, 0, 0, 0, 0, 0, 0, 0);  gn[2]  = 8192;
    gs[3]  = mkL(EG1, D8, 0, 0, 2, Pd + 3 * PSZ, gdb + 384, 0, 1, D4, ED4, 0, 0, 0); gn[3]  = 8192;
    gs[4]  = mkL(ED4, 0, 0, EG1, 1, Pd + 4 * PSZ, gdb + 512, 0, 0, 0, 0, 0, 0, 0);  gn[4]  = 4096;
    gs[5]  = mkL(EG1, D4, 0, 0, 1, Pd + 5 * PSZ, gdb + 640, 0, 1, D2, ED2, 0, 0, 0); gn[5]  = 4096;
    gs[6]  = mkL(ED2, 0, 0, EG1, 0, Pl + 0 * PSZ, glb + 0,   0, 0, 0, 0, 0, 0, 0);  gn[6]  = 2048;
    gs[7]  = mkL(EG1, D2, 0, 0, 0, Pl + 1 * PSZ, glb + 128, 0, 2, GU, EG2, D4, 0, 0); gn[7] = 2048;
    gs[8]  = mkL(EG2, 0, 0, EG1, 1, Pu + 0 * PSZ, gub + 0,   0, 0, 0, 0, 0, 0, 0);  gn[8]  = 4096;
    gs[9]  = mkL(EG1, GU, 0, 0, 1, Pu + 1 * PSZ, gub + 128, 0, 2, G2, EG2, D8, 0, 0); gn[9] = 4096;
    gs[10] = mkL(EG2, 0, 0, EG1, 2, Pu + 2 * PSZ, gub + 256, 0, 0, 0, 0, 0, 0, 0);  gn[10] = 8192;
    gs[11] = mkL(EG1, G2, 0, 0, 2, Pu + 3 * PSZ, gub + 384, 0, 2, GU, EG2, BUF0, 0, 0); gn[11] = 8192;
    gs[12] = mkL(EG2, 0, 0, EG1, 3, Pu + 4 * PSZ, gub + 512, 0, 0, 0, 0, 0, 0, 0);  gn[12] = 16384;
    gs[13] = mkL(EG1, GU, 0, EB0, 3, Pu + 5 * PSZ, gub + 640, 0, 0, 0, 0, 0, 0, 0); gn[13] = 16384;

    // ---- local branch: 30 steps ----
    LArgs ls[30];
    for (int i = 0; i < 15; ++i) {
        const ushort* P1 = Pr + (size_t)(2 * i) * PSZ;
        const ushort* P2 = Pr + (size_t)(2 * i + 1) * PSZ;
        const float* b1 = lrb + (size_t)i * 256;
        const float* b2 = b1 + 128;
        if ((i & 1) == 0) {   // lap block on L (level index 4)
            ls[2 * i]     = mkL(LE1, 0, 0, LE2, 4, P1, b1, 0, 0, 0, 0, 0, 0, 0);
            ls[2 * i + 1] = mkL(LE2, LB, (i == 14) ? nullptr : LB, LE1, 4, P2, b2,
                                (i <= 12) ? (ACC + i * 128) : nullptr, 0, 0, 0, 0, 0, 0);
        } else {              // avg block: rank-1 term folded in-kernel
            ls[2 * i]     = mkL(LE1, 0, 0, LE2, -1, P1, b1, ACC + i * 128, 0, 0, 0, 0,
                                ACC + (i - 1) * 128, lrW + (size_t)(2 * i) * WSZ + F * F);
            ls[2 * i + 1] = mkL(LE2, LB, LB, LE1, -1, P2, b2, 0, 0, 0, 0, 0,
                                ACC + i * 128, lrW + (size_t)(2 * i + 1) * WSZ + F * F);
        }
    }

    // 14 dual slots (global step k || local step k), then 16 local singles
    for (int k = 0; k < 14; ++k) {
        int na = gn[k] / NR;
        dual_layer<<<na + 512, 256, 0, stream>>>(gs[k], ls[k], na);
    }
    for (int k = 14; k < 30; ++k)
        dual_layer<<<512, 256, 0, stream>>>(ls[k], ls[k], 512);

    final_kernel<<<N / 2, 256, 0, stream>>>(EB0, LE1, inputs, gW2, gb2, lW2, lb2, out, N);
}